// Round 12
// baseline (12895.927 us; speedup 1.0000x reference)
//
#include <hip/hip_runtime.h>
#include <hip/hip_bf16.h>
#include <math.h>

#define E_ 7
#define B_ 50
#define T_ 100
#define D_ 128
#define A_ 32
#define L_ 256
#define H_ 1024
#define C_ 128
#define EB_ 350
#define TB_ 5000
#define SQRTH 0.31622776601683794f

typedef __attribute__((ext_vector_type(8))) short s8v;
typedef __attribute__((ext_vector_type(4))) float f32x4;
typedef _Float16 f16x2 __attribute__((ext_vector_type(2)));
typedef __hip_bfloat16 bf16;

#define MFMA __builtin_amdgcn_mfma_f32_16x16x32_bf16

__device__ __forceinline__ int lswz(int row, int ck) {
  return (((ck & ~7) | ((ck ^ row) & 7)) << 3);
}
__device__ __forceinline__ int swzE(int r, int col) {
  const int ck = col >> 3;
  return (((ck & ~7) | ((ck ^ r) & 7)) << 3) + (col & 7);
}
__device__ __forceinline__ f16x2 relu2(f16x2 t) {
#if __has_builtin(__builtin_elementwise_max)
  const f16x2 zz = {};
  return __builtin_elementwise_max(t, zz);
#else
  t[0] = t[0] > (_Float16)0 ? t[0] : (_Float16)0;
  t[1] = t[1] > (_Float16)0 ? t[1] : (_Float16)0;
  return t;
#endif
}
__device__ __forceinline__ float fdot2a(f16x2 a, f16x2 b, float c) {
#if __has_builtin(__builtin_amdgcn_fdot2)
  return __builtin_amdgcn_fdot2(a, b, c, false);
#else
  return c + (float)a[0] * (float)b[0] + (float)a[1] * (float)b[1];
#endif
}

struct BG {
  const bf16* A[8];
  const bf16* W[8];
  const float* bias[8];
  float* Cf[8];
  bf16* Cb[8];
};

// ---------------- bf16 MFMA GEMM (validated round 2) ----------------
template<int BM, int ACT, int OUT>
__global__ __launch_bounds__(256)
void bgemm(BG g, int M, int K, int lda, int ldw, int ldc) {
  __shared__ short As[BM * 64];
  __shared__ short Ws[128 * 64];
  const short* Ap = (const short*)g.A[blockIdx.z];
  const short* Wp = (const short*)g.W[blockIdx.z];
  const int bm = blockIdx.x * BM, bn = blockIdx.y * 128;
  const int tid = threadIdx.x;
  const int wv = tid >> 6, lane = tid & 63;
  const int wm0 = (wv >> 1) * (BM / 2), wn0 = (wv & 1) * 64;
  const int l15 = lane & 15, l4 = lane >> 4;
  constexpr int FM = BM / 32;
  constexpr int AI = BM / 32;
  f32x4 acc[FM][4] = {};
  for (int k0 = 0; k0 < K; k0 += 64) {
    s8v av[AI], wvv[4];
#pragma unroll
    for (int i = 0; i < AI; ++i) {
      const int c = tid + i * 256, r = c >> 3, ck = c & 7;
      s8v v = {};
      if (bm + r < M) v = *(const s8v*)(Ap + (size_t)(bm + r) * lda + k0 + ck * 8);
      av[i] = v;
    }
#pragma unroll
    for (int i = 0; i < 4; ++i) {
      const int c = tid + i * 256, r = c >> 3, ck = c & 7;
      wvv[i] = *(const s8v*)(Wp + (size_t)(bn + r) * ldw + k0 + ck * 8);
    }
    __syncthreads();
#pragma unroll
    for (int i = 0; i < AI; ++i) {
      const int c = tid + i * 256, r = c >> 3, ck = c & 7;
      *(s8v*)(As + r * 64 + ((ck ^ (r & 7)) << 3)) = av[i];
    }
#pragma unroll
    for (int i = 0; i < 4; ++i) {
      const int c = tid + i * 256, r = c >> 3, ck = c & 7;
      *(s8v*)(Ws + r * 64 + ((ck ^ (r & 7)) << 3)) = wvv[i];
    }
    __syncthreads();
#pragma unroll
    for (int ks = 0; ks < 2; ++ks) {
      s8v af[FM], bfr[4];
#pragma unroll
      for (int m = 0; m < FM; ++m) {
        const int r = wm0 + m * 16 + l15, ck = ks * 4 + l4;
        af[m] = *(const s8v*)(As + r * 64 + ((ck ^ (r & 7)) << 3));
      }
#pragma unroll
      for (int n = 0; n < 4; ++n) {
        const int r = wn0 + n * 16 + l15, ck = ks * 4 + l4;
        bfr[n] = *(const s8v*)(Ws + r * 64 + ((ck ^ (r & 7)) << 3));
      }
#pragma unroll
      for (int m = 0; m < FM; ++m)
#pragma unroll
        for (int n = 0; n < 4; ++n)
          acc[m][n] = MFMA(af[m], bfr[n], acc[m][n], 0, 0, 0);
    }
    __syncthreads();
  }
  const float* bias = g.bias[blockIdx.z];
  float* Cf = g.Cf[blockIdx.z];
  bf16* Cb = g.Cb[blockIdx.z];
#pragma unroll
  for (int n = 0; n < 4; ++n) {
    const int col = bn + wn0 + n * 16 + l15;
    const float bv = bias ? bias[col] : 0.f;
#pragma unroll
    for (int m = 0; m < FM; ++m) {
#pragma unroll
      for (int j = 0; j < 4; ++j) {
        const int row = bm + wm0 + m * 16 + l4 * 4 + j;
        if (row < M) {
          float v = acc[m][n][j] + bv;
          if (ACT == 1) v = fmaxf(v, 0.f);
          if (ACT == 2) v = tanhf(v);
          if (OUT == 0) Cf[(size_t)row * ldc + col] = v;
          if (OUT == 1) Cb[(size_t)row * ldc + col] = __float2bfloat16(v);
        }
      }
    }
  }
}

// ---------------- conversions / packing ----------------
__global__ __launch_bounds__(256)
void cvtT_kernel(const float* __restrict__ src, bf16* __restrict__ dst,
                 int K, int N, long ss, long ds) {
  __shared__ float t[32][33];
  src += (size_t)blockIdx.z * ss;
  dst += (size_t)blockIdx.z * ds;
  const int n0 = blockIdx.x * 32, k0 = blockIdx.y * 32;
  const int tx = threadIdx.x & 31, ty = threadIdx.x >> 5;
#pragma unroll
  for (int i = 0; i < 4; ++i)
    t[ty + 8 * i][tx] = src[(size_t)(k0 + ty + 8 * i) * N + n0 + tx];
  __syncthreads();
#pragma unroll
  for (int i = 0; i < 4; ++i)
    dst[(size_t)(n0 + ty + 8 * i) * K + k0 + tx] = __float2bfloat16(t[tx][ty + 8 * i]);
}

struct B4 { bf16 a, b, c, d; };
__global__ __launch_bounds__(256)
void cvt_kernel(const float* __restrict__ s, bf16* __restrict__ d, int n4) {
  const int i = blockIdx.x * 256 + threadIdx.x;
  if (i < n4) {
    const float4 v = ((const float4*)s)[i];
    B4 o = {__float2bfloat16(v.x), __float2bfloat16(v.y),
            __float2bfloat16(v.z), __float2bfloat16(v.w)};
    ((B4*)d)[i] = o;
  }
}

// pack fp32 [K][N] row-major -> bf16 fragment-major [nt][kt][lane][8]
__global__ __launch_bounds__(256)
void packW(const float* __restrict__ src, bf16* __restrict__ dst, int K, int N) {
  const int idx = blockIdx.x * 256 + threadIdx.x;
  if (idx >= K * N) return;
  const int k = idx / N, n = idx - k * N;
  const size_t fo = ((size_t)(n >> 4) * (K >> 5) + (k >> 5)) * 512 +
                    (((k >> 3) & 3) << 7) + ((n & 15) << 3) + (k & 7);
  dst[fo] = __float2bfloat16(src[idx]);
}

__global__ __launch_bounds__(256)
void packWz(const float* __restrict__ act_w, bf16* __restrict__ hi, bf16* __restrict__ lo) {
  const int idx = blockIdx.x * 256 + threadIdx.x;
  if (idx >= E_ * 65536) return;
  const int e = idx >> 16, rem = idx & 65535, k = rem >> 8, n = rem & 255;
  const float w = act_w[(size_t)e * 416 * 256 + (size_t)k * 256 + n];
  const bf16 h = __float2bfloat16(w);
  const size_t fo = (size_t)e * 65536 + ((size_t)(n >> 4) * 8 + (k >> 5)) * 512 +
                    (((k >> 3) & 3) << 7) + ((n & 15) << 3) + (k & 7);
  hi[fo] = h;
  lo[fo] = __float2bfloat16(w - __bfloat162float(h));
}

__global__ __launch_bounds__(256)
void ax_build(const float* __restrict__ actions, const float* __restrict__ xs,
              bf16* __restrict__ dst) {
  const int idx = blockIdx.x * 256 + threadIdx.x;
  if (idx >= E_ * TB_ * 192) return;
  const int k = idx % 192;
  const int r = (idx / 192) % TB_;
  const int e = idx / (192 * TB_);
  float v = 0.f;
  if (k < 32) v = actions[((size_t)e * TB_ + r) * A_ + k];
  else if (k < 160) v = xs[((size_t)e * TB_ + r) * D_ + (k - 32)];
  dst[idx] = __float2bfloat16(v);
}

__global__ __launch_bounds__(256)
void waxT_build(const float* __restrict__ act_w, bf16* __restrict__ dst) {
  const int idx = blockIdx.x * 256 + threadIdx.x;
  if (idx >= E_ * 256 * 192) return;
  const int k = idx % 192;
  const int n = (idx / 192) % 256;
  const int e = idx / (192 * 256);
  float v = (k < 160) ? act_w[(size_t)e * 416 * 256 + (size_t)(256 + k) * 256 + n] : 0.f;
  dst[idx] = __float2bfloat16(v);
}

// g weights -> [arr][hpair][l][2] fp16 (lane = l coalesced)
__global__ __launch_bounds__(256)
void gpack2(const float* __restrict__ gw1, const float* __restrict__ gb1,
            const float* __restrict__ gw2, _Float16* __restrict__ dst) {
  const int idx = blockIdx.x * 256 + threadIdx.x;
  if (idx >= 3 * 512 * 256 * 2) return;
  const int i = idx & 1;
  const int l = (idx >> 1) & 255;
  const int hpg = (idx >> 9) & 511;
  const int arr = idx >> 18;
  const float* s = arr == 0 ? gw1 : (arr == 1 ? gb1 : gw2);
  dst[idx] = (_Float16)s[(size_t)l * 1024 + hpg * 2 + i];
}

// ---------------- q/KL (+z0 split hi/lo) ----------------
__global__ __launch_bounds__(256)
void qkl_kernel(const float* __restrict__ ctx, int rows, int row_off, int ctx_estride,
                const float* __restrict__ qw, const float* __restrict__ qb,
                const float* __restrict__ pm, const float* __restrict__ pl,
                const float* __restrict__ eps0, bf16* __restrict__ z0hi,
                bf16* __restrict__ z0lo, float* __restrict__ logqp) {
  __shared__ float cx[16][128];
  __shared__ float red[16];
  const int e = blockIdx.y;
  const int r0 = blockIdx.x * 16;
  const int tid = threadIdx.x;
  {
    const int r = tid >> 4, c = (tid & 15) * 8;
    float4 v0 = make_float4(0.f, 0.f, 0.f, 0.f), v1 = v0;
    if (r0 + r < rows) {
      const float* src = ctx + (size_t)e * ctx_estride + (size_t)(r0 + r) * C_ + c;
      v0 = *(const float4*)src;
      v1 = *(const float4*)(src + 4);
    }
    *(float4*)&cx[r][c] = v0;
    *(float4*)&cx[r][c + 4] = v1;
  }
  if (tid < 16) red[tid] = 0.f;
  __syncthreads();
  const int j = tid;
  const float* w = qw + (size_t)e * C_ * 512;
  float am_[16] = {};
  float al_[16] = {};
  for (int k0 = 0; k0 < C_; k0 += 4) {
    float wm[4], wl[4];
#pragma unroll
    for (int q = 0; q < 4; ++q) {
      wm[q] = w[(size_t)(k0 + q) * 512 + j];
      wl[q] = w[(size_t)(k0 + q) * 512 + 256 + j];
    }
#pragma unroll
    for (int r = 0; r < 16; ++r) {
      const float4 cv = *(const float4*)&cx[r][k0];
      const float cc[4] = {cv.x, cv.y, cv.z, cv.w};
#pragma unroll
      for (int q = 0; q < 4; ++q) {
        am_[r] = fmaf(cc[q], wm[q], am_[r]);
        al_[r] = fmaf(cc[q], wl[q], al_[r]);
      }
    }
  }
  const float qbm = qb[(size_t)e * 512 + j];
  const float qbl = qb[(size_t)e * 512 + 256 + j];
  const float pmv = pm[(size_t)e * L_ + j];
  const float plv = pl[(size_t)e * L_ + j];
  const float inv2e = 0.5f * expf(-2.f * plv);
#pragma unroll
  for (int r = 0; r < 16; ++r) {
    float kl = 0.f;
    if (r0 + r < rows) {
      const float qm_ = am_[r] + qbm;
      const float ql_ = al_[r] + qbl;
      const float dm = qm_ - pmv;
      kl = plv - ql_ + (expf(2.f * ql_) + dm * dm) * inv2e - 0.5f;
      const int gi = row_off + r0 + r;
      if (gi < B_) {
        const size_t zi = ((size_t)e * B_ + gi) * L_ + j;
        const float z0 = qm_ + expf(ql_) * eps0[zi];
        const bf16 h = __float2bfloat16(z0);
        z0hi[zi] = h;
        z0lo[zi] = __float2bfloat16(z0 - __bfloat162float(h));
      }
    }
    for (int off = 32; off; off >>= 1) kl += __shfl_xor(kl, off, 64);
    if ((tid & 63) == 0) atomicAdd(&red[r], kl);
  }
  __syncthreads();
  if (tid < 16 && r0 + tid < rows) atomicAdd(&logqp[e], red[tid] * (1.0f / B_));
}

// ---------------- bootstrap kernels (validated round 6) ----------------
// k1_act: zP/zPb for t=0 from z0 split. grid (4 rb13, 2 nt128, 7 e)
__global__ __launch_bounds__(256, 2)
void k1_act(const bf16* __restrict__ zhi, const bf16* __restrict__ zlo,
            const bf16* __restrict__ wzh, const bf16* __restrict__ wzl,
            const float* __restrict__ axw, float* __restrict__ zP,
            bf16* __restrict__ zPb, int t) {
  __shared__ short Ah[16 * 256];
  __shared__ short Al[16 * 256];
  const int e = blockIdx.z, rb = blockIdx.x, nb = blockIdx.y * 128;
  const int r0 = rb * 13;
  const int nrows = (50 - r0 < 13) ? (50 - r0) : 13;
  const int tid = threadIdx.x, lane = tid & 63, wv = tid >> 6;
  const int l15 = lane & 15, l4 = lane >> 4;
  const short* zh = (const short*)zhi + (size_t)(e * 50 + r0) * 256;
  const short* zl = (const short*)zlo + (size_t)(e * 50 + r0) * 256;
#pragma unroll
  for (int i = 0; i < 2; ++i) {
    const int lin = tid + i * 256, row = lin >> 5, ck = lin & 31;
    s8v vh = {}, vl = {};
    if (row < nrows) {
      vh = *(const s8v*)(zh + row * 256 + ck * 8);
      vl = *(const s8v*)(zl + row * 256 + ck * 8);
    }
    *(s8v*)(Ah + row * 256 + lswz(row, ck)) = vh;
    *(s8v*)(Al + row * 256 + lswz(row, ck)) = vl;
  }
  __syncthreads();
  const short* Bh = (const short*)wzh + (size_t)e * 65536;
  const short* Bl = (const short*)wzl + (size_t)e * 65536;
  f32x4 acc[2] = {};
#pragma unroll
  for (int kt = 0; kt < 8; ++kt) {
    const int ck = kt * 4 + l4;
    const s8v ah = *(const s8v*)(Ah + l15 * 256 + lswz(l15, ck));
    const s8v al = *(const s8v*)(Al + l15 * 256 + lswz(l15, ck));
#pragma unroll
    for (int nt = 0; nt < 2; ++nt) {
      const int ng = nb + wv * 32 + nt * 16;
      const size_t bo = ((size_t)(ng >> 4) * 8 + kt) * 512 + lane * 8;
      const s8v bh = *(const s8v*)(Bh + bo);
      const s8v bl = *(const s8v*)(Bl + bo);
      acc[nt] = MFMA(ah, bh, acc[nt], 0, 0, 0);
      acc[nt] = MFMA(al, bh, acc[nt], 0, 0, 0);
      acc[nt] = MFMA(ah, bl, acc[nt], 0, 0, 0);
    }
  }
#pragma unroll
  for (int nt = 0; nt < 2; ++nt) {
    const int col = nb + wv * 32 + nt * 16 + l15;
#pragma unroll
    for (int j = 0; j < 4; ++j) {
      const int row = l4 * 4 + j;
      if (row < nrows) {
        const int gr = e * 50 + r0 + row;
        const float v = acc[nt][j] + axw[((size_t)e * TB_ + t * 50 + r0 + row) * 256 + col];
        zP[(size_t)gr * 256 + col] = v;
        zPb[(size_t)gr * 256 + col] = __float2bfloat16(v);
      }
    }
  }
}

// k2_l1: fh1 = relu(zPb @ W1fh + b1). grid (22 rb16, 16 nt128)
__global__ __launch_bounds__(256, 2)
void k2_l1(const bf16* __restrict__ zPb, const bf16* __restrict__ w1f,
           const float* __restrict__ fb1, const float* __restrict__ hb1,
           bf16* __restrict__ fh1) {
  __shared__ short As[16 * 256];
  const int rb = blockIdx.x, nb = blockIdx.y * 128;
  const int r0 = rb * 16;
  const int tid = threadIdx.x, lane = tid & 63, wv = tid >> 6;
  const int l15 = lane & 15, l4 = lane >> 4;
#pragma unroll
  for (int i = 0; i < 2; ++i) {
    const int lin = tid + i * 256, row = lin >> 5, ck = lin & 31;
    s8v v = {};
    if (r0 + row < EB_)
      v = *(const s8v*)((const short*)zPb + (size_t)(r0 + row) * 256 + ck * 8);
    *(s8v*)(As + row * 256 + lswz(row, ck)) = v;
  }
  __syncthreads();
  f32x4 acc[2] = {};
#pragma unroll
  for (int kt = 0; kt < 8; ++kt) {
    const int ck = kt * 4 + l4;
    const s8v a = *(const s8v*)(As + l15 * 256 + lswz(l15, ck));
#pragma unroll
    for (int nt = 0; nt < 2; ++nt) {
      const int ng = nb + wv * 32 + nt * 16;
      const s8v b = *(const s8v*)((const short*)w1f + ((size_t)(ng >> 4) * 8 + kt) * 512 + lane * 8);
      acc[nt] = MFMA(a, b, acc[nt], 0, 0, 0);
    }
  }
#pragma unroll
  for (int nt = 0; nt < 2; ++nt) {
    const int col = nb + wv * 32 + nt * 16 + l15;
    const float bv = (col < 1024) ? fb1[col] : hb1[col - 1024];
#pragma unroll
    for (int j = 0; j < 4; ++j) {
      const int row = r0 + l4 * 4 + j;
      if (row < EB_)
        fh1[(size_t)row * 2048 + col] = __float2bfloat16(fmaxf(acc[nt][j] + bv, 0.f));
    }
  }
}

// ---------------- scan slots ----------------
// Slot A: fh2 = tanh(fh1 @ W2 + b2). block-diagonal f/h. grid (22 rb16, 16 nt128)
__global__ __launch_bounds__(256, 2)
void k3_l2(const bf16* __restrict__ fh1, const bf16* __restrict__ w2f,
           const float* __restrict__ fb2, const float* __restrict__ hb2,
           bf16* __restrict__ fh2) {
  __shared__ short As[16 * 1024];
  const int rb = blockIdx.x, nbl = blockIdx.y;
  const int nb = nbl * 128, r0 = rb * 16;
  const int half = (nbl >= 8) ? 1024 : 0;
  const int tid = threadIdx.x, lane = tid & 63, wv = tid >> 6;
  const int l15 = lane & 15, l4 = lane >> 4;
#pragma unroll
  for (int i = 0; i < 8; ++i) {
    const int lin = tid + i * 256, row = lin >> 7, ck = lin & 127;
    s8v v = {};
    if (r0 + row < EB_)
      v = *(const s8v*)((const short*)fh1 + (size_t)(r0 + row) * 2048 + half + ck * 8);
    *(s8v*)(As + row * 1024 + lswz(row, ck)) = v;
  }
  __syncthreads();
  f32x4 acc[2] = {};
#pragma unroll 4
  for (int kt = 0; kt < 32; ++kt) {
    const int ck = kt * 4 + l4;
    const s8v a = *(const s8v*)(As + l15 * 1024 + lswz(l15, ck));
#pragma unroll
    for (int nt = 0; nt < 2; ++nt) {
      const int ng = nb + wv * 32 + nt * 16;
      const s8v b = *(const s8v*)((const short*)w2f + ((size_t)(ng >> 4) * 32 + kt) * 512 + lane * 8);
      acc[nt] = MFMA(a, b, acc[nt], 0, 0, 0);
    }
  }
#pragma unroll
  for (int nt = 0; nt < 2; ++nt) {
    const int col = nb + wv * 32 + nt * 16 + l15;
    const float bv = half ? hb2[col - 1024] : fb2[col];
#pragma unroll
    for (int j = 0; j < 4; ++j) {
      const int row = r0 + l4 * 4 + j;
      if (row < EB_)
        fh2[(size_t)row * 2048 + col] = __float2bfloat16(tanhf(acc[nt][j] + bv));
    }
  }
}

// Slot B: L3 + g + epilogue + act(t+1) + L1(t+1). grid 28 (4 q x 7 e), 512 thr.
__global__ __launch_bounds__(512)
void kfin(const bf16* __restrict__ fh2, const bf16* __restrict__ w3f,
          const float* __restrict__ fb3, const float* __restrict__ hb3,
          const _Float16* __restrict__ gpk, const float* __restrict__ gb2,
          float* __restrict__ zP, const float* __restrict__ dw,
          const float* __restrict__ axw, const bf16* __restrict__ wzh,
          const bf16* __restrict__ wzl, const bf16* __restrict__ w1f,
          const float* __restrict__ fb1, const float* __restrict__ hb1,
          bf16* __restrict__ zs_bf, bf16* __restrict__ fh1,
          float* __restrict__ logqp, int t, int doAct) {
  __shared__ short As[16 * 1024];
  __shared__ float zst[16 * 256];
  __shared__ float gvt[16 * 256];
  __shared__ short Zh[16 * 256];
  __shared__ short Zl[16 * 256];
  __shared__ short Pb[16 * 256];
  __shared__ float red[8];
  const int bx = blockIdx.x;
  const int e = bx >> 2, q = bx & 3;
  const int nr = (q < 2) ? 13 : 12;
  const int b0 = (q < 2) ? q * 13 : 26 + (q - 2) * 12;
  const int R0 = e * 50 + b0;
  const int tid = threadIdx.x, wave = tid >> 6, lane = tid & 63;
  const int l15 = lane & 15, l4 = lane >> 4;
  // stage z (current) f32
  for (int i = tid; i < 4096; i += 512) {
    const int r = i >> 8, c = i & 255;
    zst[i] = (r < nr) ? zP[(size_t)(R0 + r) * 256 + c] : 0.f;
  }
  // ---- L3f ----
  for (int i = tid; i < 2048; i += 512) {
    const int row = i >> 7, ck = i & 127;
    s8v v = {};
    if (row < nr) v = *(const s8v*)((const short*)fh2 + (size_t)(R0 + row) * 2048 + ck * 8);
    *(s8v*)(As + row * 1024 + lswz(row, ck)) = v;
  }
  __syncthreads();
  f32x4 accF[2] = {}, accH[2] = {};
#pragma unroll 4
  for (int kt = 0; kt < 32; ++kt) {
    const int ck = kt * 4 + l4;
    const s8v a = *(const s8v*)(As + l15 * 1024 + lswz(l15, ck));
#pragma unroll
    for (int cc = 0; cc < 2; ++cc) {
      const int ct = wave * 2 + cc;
      const s8v b = *(const s8v*)((const short*)w3f + ((size_t)(ct * 32 + kt)) * 512 + (size_t)lane * 8);
      accF[cc] = MFMA(a, b, accF[cc], 0, 0, 0);
    }
  }
  __syncthreads();
  // ---- L3h ----
  for (int i = tid; i < 2048; i += 512) {
    const int row = i >> 7, ck = i & 127;
    s8v v = {};
    if (row < nr) v = *(const s8v*)((const short*)fh2 + (size_t)(R0 + row) * 2048 + 1024 + ck * 8);
    *(s8v*)(As + row * 1024 + lswz(row, ck)) = v;
  }
  __syncthreads();
#pragma unroll 4
  for (int kt = 0; kt < 32; ++kt) {
    const int ck = kt * 4 + l4;
    const s8v a = *(const s8v*)(As + l15 * 1024 + lswz(l15, ck));
#pragma unroll
    for (int cc = 0; cc < 2; ++cc) {
      const int ct = 16 + wave * 2 + cc;
      const s8v b = *(const s8v*)((const short*)w3f + ((size_t)(ct * 32 + kt)) * 512 + (size_t)lane * 8);
      accH[cc] = MFMA(a, b, accH[cc], 0, 0, 0);
    }
  }
  // ---- g (2-way h-split; l = tid&255, hh = wave>>2) ----
  {
    const int hh = wave >> 2;
    const int l = tid & 255;
    f16x2 z2[13];
    float ga[13];
#pragma unroll
    for (int r = 0; r < 13; ++r) {
      const _Float16 z = (_Float16)zst[r * 256 + l];
      z2[r] = f16x2{z, z};
      ga[r] = 0.f;
    }
    const _Float16* gb_ = gpk + (size_t)(hh * 256) * 512 + (size_t)l * 2;
    for (int k = 0; k < 256; ++k) {
      const size_t o = (size_t)k * 512;
      const f16x2 w1 = *(const f16x2*)(gb_ + o);
      const f16x2 b1 = *(const f16x2*)(gb_ + 262144 + o);
      const f16x2 w2 = *(const f16x2*)(gb_ + 524288 + o);
#pragma unroll
      for (int r = 0; r < 13; ++r)
        ga[r] = fdot2a(relu2(z2[r] * w1 + b1), w2, ga[r]);
    }
    if (hh == 0) {
#pragma unroll
      for (int r = 0; r < 13; ++r) gvt[r * 256 + l] = ga[r];
    }
    __syncthreads();
    if (hh == 1) {
#pragma unroll
      for (int r = 0; r < 13; ++r) gvt[r * 256 + l] += ga[r] + gb2[l];
    }
  }
  __syncthreads();
  // ---- epilogue ----
  float lr = 0.f;
#pragma unroll
  for (int cc = 0; cc < 2; ++cc) {
    const int col = (wave * 2 + cc) * 16 + l15;
    const float fb3v = fb3[col], hb3v = hb3[col];
#pragma unroll
    for (int j = 0; j < 4; ++j) {
      const int r = l4 * 4 + j;
      if (r < nr) {
        const float fv = accF[cc][j] + fb3v;
        const float hv = accH[cc][j] + hb3v;
        const float gv = gvt[r * 256 + col];
        const float u = (fv - hv) / gv;
        lr += u * u;
        const float zn = zst[r * 256 + col] + 0.1f * fv +
            gv * (SQRTH * dw[(size_t)t * (EB_ * 256) + (size_t)(R0 + r) * 256 + col]);
        zst[r * 256 + col] = zn;
        zs_bf[((size_t)e * TB_ + t * 50 + b0 + r) * 256 + col] = __float2bfloat16(zn);
      }
    }
  }
#pragma unroll
  for (int o = 32; o; o >>= 1) lr += __shfl_xor(lr, o, 64);
  if (lane == 0) red[wave] = lr;
  __syncthreads();
  if (tid == 0) {
    float s = 0.f;
    for (int w = 0; w < 8; ++w) s += red[w];
    atomicAdd(&logqp[e], 0.001f * s);
  }
  if (!doAct) return;
  __syncthreads();
  // ---- build z hi/lo (swizzled) from zst ----
  {
    const int row = tid >> 5, ck = tid & 31;
    const int base = row * 256;
    const int so = base + lswz(row, ck);
#pragma unroll
    for (int m = 0; m < 8; ++m) {
      const float f = zst[base + ck * 8 + m];
      const bf16 h = __float2bfloat16(f);
      const bf16 lo = __float2bfloat16(f - __bfloat162float(h));
      *(bf16*)&Zh[so + m] = h;
      *(bf16*)&Zl[so + m] = lo;
    }
  }
  __syncthreads();
  // ---- act(t+1) ----
#pragma unroll
  for (int cc = 0; cc < 2; ++cc) {
    const int ct = wave * 2 + cc;
    f32x4 acc = {};
#pragma unroll
    for (int kt = 0; kt < 8; ++kt) {
      const int ck = kt * 4 + l4;
      const s8v ah = *(const s8v*)(Zh + l15 * 256 + lswz(l15, ck));
      const s8v al = *(const s8v*)(Zl + l15 * 256 + lswz(l15, ck));
      const size_t bo = ((size_t)(ct * 8 + kt)) * 512 + (size_t)lane * 8;
      const s8v bh = *(const s8v*)((const short*)wzh + (size_t)e * 65536 + bo);
      const s8v bl = *(const s8v*)((const short*)wzl + (size_t)e * 65536 + bo);
      acc = MFMA(ah, bh, acc, 0, 0, 0);
      acc = MFMA(al, bh, acc, 0, 0, 0);
      acc = MFMA(ah, bl, acc, 0, 0, 0);
    }
    const int col = ct * 16 + l15;
#pragma unroll
    for (int j = 0; j < 4; ++j) {
      const int r = l4 * 4 + j;
      float v = 0.f;
      if (r < nr) {
        v = acc[j] + axw[((size_t)e * TB_ + (t + 1) * 50 + b0 + r) * 256 + col];
        zP[(size_t)(R0 + r) * 256 + col] = v;
      }
      *(bf16*)&Pb[r * 256 + swzE(r, col)] = __float2bfloat16(v);
    }
  }
  __syncthreads();
  // ---- L1(t+1) ----
  for (int c = 0; c < 16; ++c) {
    const int gct = wave * 16 + c;
    f32x4 acc = {};
#pragma unroll
    for (int kt = 0; kt < 8; ++kt) {
      const int ck = kt * 4 + l4;
      const s8v a = *(const s8v*)(Pb + l15 * 256 + lswz(l15, ck));
      const s8v b = *(const s8v*)((const short*)w1f + ((size_t)(gct * 8 + kt)) * 512 + (size_t)lane * 8);
      acc = MFMA(a, b, acc, 0, 0, 0);
    }
    const int col = gct * 16 + l15;
    const float bv = (col < 1024) ? fb1[col] : hb1[col - 1024];
#pragma unroll
    for (int j = 0; j < 4; ++j) {
      const int r = l4 * 4 + j;
      if (r < nr)
        fh1[(size_t)(R0 + r) * 2048 + col] = __float2bfloat16(fmaxf(acc[j] + bv, 0.f));
    }
  }
}

__global__ void init_kernel(float* logqp) {
  if (threadIdx.x < E_) logqp[threadIdx.x] = 0.f;
}

extern "C" void kernel_launch(void* const* d_in, const int* in_sizes, int n_in,
                              void* d_out, int out_size, void* d_ws, size_t ws_size,
                              hipStream_t stream) {
  (void)in_sizes; (void)n_in; (void)out_size;
  const float* enc_w1 = (const float*)d_in[0];
  const float* enc_b1 = (const float*)d_in[1];
  const float* enc_w2 = (const float*)d_in[2];
  const float* enc_b2 = (const float*)d_in[3];
  const float* enc_w3 = (const float*)d_in[4];
  const float* enc_b3 = (const float*)d_in[5];
  const float* qz0_w  = (const float*)d_in[6];
  const float* qz0_b  = (const float*)d_in[7];
  const float* act_w  = (const float*)d_in[8];
  const float* act_b  = (const float*)d_in[9];
  const float* proj_w1 = (const float*)d_in[10];
  const float* proj_b1 = (const float*)d_in[11];
  const float* proj_w2 = (const float*)d_in[12];
  const float* proj_b2 = (const float*)d_in[13];
  const float* proj_w3 = (const float*)d_in[14];
  const float* proj_b3 = (const float*)d_in[15];
  const float* f_w1 = (const float*)d_in[16];
  const float* f_b1 = (const float*)d_in[17];
  const float* f_w2 = (const float*)d_in[18];
  const float* f_b2 = (const float*)d_in[19];
  const float* f_w3 = (const float*)d_in[20];
  const float* f_b3 = (const float*)d_in[21];
  const float* h_w1 = (const float*)d_in[22];
  const float* h_b1 = (const float*)d_in[23];
  const float* h_w2 = (const float*)d_in[24];
  const float* h_b2 = (const float*)d_in[25];
  const float* h_w3 = (const float*)d_in[26];
  const float* h_b3 = (const float*)d_in[27];
  const float* g_w1 = (const float*)d_in[28];
  const float* g_b1 = (const float*)d_in[29];
  const float* g_w2 = (const float*)d_in[30];
  const float* g_b2 = (const float*)d_in[31];
  const float* pz0_mean   = (const float*)d_in[32];
  const float* pz0_logstd = (const float*)d_in[33];
  const float* xs      = (const float*)d_in[34];
  const float* actions = (const float*)d_in[35];
  const float* eps_z0  = (const float*)d_in[36];
  const float* dw      = (const float*)d_in[37];

  float* out = (float*)d_out;
  float* logqp = out;
  float* pred = out + E_;

  char* base = (char*)d_ws;
  size_t off = 0;
  auto alloc = [&](size_t bytes) {
    void* p = base + off;
    off = (off + bytes + 255) & ~(size_t)255;
    return p;
  };
  bf16* zhi    = (bf16*)alloc((size_t)EB_ * 256 * 2);
  bf16* zlo    = (bf16*)alloc((size_t)EB_ * 256 * 2);
  float* zP    = (float*)alloc((size_t)EB_ * 256 * 4);
  bf16* zPb    = (bf16*)alloc((size_t)EB_ * 256 * 2);
  bf16* fh1    = (bf16*)alloc((size_t)EB_ * 2048 * 2);
  bf16* fh2    = (bf16*)alloc((size_t)EB_ * 2048 * 2);
  bf16* zs_bf  = (bf16*)alloc((size_t)E_ * T_ * B_ * 256 * 2);
  float* axw   = (float*)alloc((size_t)E_ * TB_ * 256 * 4 + 256 * 64);
  bf16* ax_bf  = (bf16*)alloc((size_t)E_ * TB_ * 192 * 2);
  bf16* waxT   = (bf16*)alloc((size_t)E_ * 256 * 192 * 2);
  bf16* wzh    = (bf16*)alloc((size_t)E_ * 65536 * 2);
  bf16* wzl    = (bf16*)alloc((size_t)E_ * 65536 * 2);
  bf16* w1f    = (bf16*)alloc((size_t)2048 * 256 * 2);
  bf16* w2f    = (bf16*)alloc((size_t)2048 * 1024 * 2);
  bf16* w3f    = (bf16*)alloc((size_t)512 * 1024 * 2);
  _Float16* gpk = (_Float16*)alloc((size_t)3 * 512 * 256 * 2 * 2);
  bf16* xs_bf  = (bf16*)alloc((size_t)E_ * TB_ * D_ * 2);
  bf16* ew1T = (bf16*)alloc((size_t)E_ * D_ * H_ * 2);
  bf16* ew2T = (bf16*)alloc((size_t)E_ * H_ * H_ * 2);
  bf16* ew3T = (bf16*)alloc((size_t)E_ * H_ * C_ * 2);
  bf16* pw1T = (bf16*)alloc((size_t)E_ * L_ * H_ * 2);
  bf16* pw2T = (bf16*)alloc((size_t)E_ * H_ * H_ * 2);
  bf16* pw3T = (bf16*)alloc((size_t)E_ * H_ * D_ * 2);
  const size_t per_row = (size_t)E_ * (H_ * 2 * 2 + C_ * 4);
  size_t remain = (ws_size > off + 4096) ? (ws_size - off - 4096) : 0;
  int CH = (int)(remain / per_row);
  if (CH > 2500) CH = 2500;
  if (CH < 64) CH = 64;
  bf16* bufA = (bf16*)alloc((size_t)E_ * CH * H_ * 2);
  bf16* bufB = (bf16*)alloc((size_t)E_ * CH * H_ * 2);
  float* bufC = (float*)alloc((size_t)E_ * CH * C_ * 4);

  init_kernel<<<dim3(1), dim3(64), 0, stream>>>(logqp);

  const dim3 cb256(256);
  cvt_kernel<<<dim3((E_ * TB_ * D_ / 4 + 255) / 256), cb256, 0, stream>>>(xs, xs_bf, E_ * TB_ * D_ / 4);
  cvtT_kernel<<<dim3(H_ / 32, D_ / 32, E_), cb256, 0, stream>>>(enc_w1, ew1T, D_, H_, (long)D_ * H_, (long)D_ * H_);
  cvtT_kernel<<<dim3(H_ / 32, H_ / 32, E_), cb256, 0, stream>>>(enc_w2, ew2T, H_, H_, (long)H_ * H_, (long)H_ * H_);
  cvtT_kernel<<<dim3(C_ / 32, H_ / 32, E_), cb256, 0, stream>>>(enc_w3, ew3T, H_, C_, (long)H_ * C_, (long)H_ * C_);
  cvtT_kernel<<<dim3(H_ / 32, L_ / 32, E_), cb256, 0, stream>>>(proj_w1, pw1T, L_, H_, (long)L_ * H_, (long)L_ * H_);
  cvtT_kernel<<<dim3(H_ / 32, H_ / 32, E_), cb256, 0, stream>>>(proj_w2, pw2T, H_, H_, (long)H_ * H_, (long)H_ * H_);
  cvtT_kernel<<<dim3(D_ / 32, H_ / 32, E_), cb256, 0, stream>>>(proj_w3, pw3T, H_, D_, (long)H_ * D_, (long)H_ * D_);
  ax_build<<<dim3((E_ * TB_ * 192 + 255) / 256), cb256, 0, stream>>>(actions, xs, ax_bf);
  waxT_build<<<dim3((E_ * 256 * 192 + 255) / 256), cb256, 0, stream>>>(act_w, waxT);
  packWz<<<dim3((E_ * 65536 + 255) / 256), cb256, 0, stream>>>(act_w, wzh, wzl);
  packW<<<dim3((256 * 1024 + 255) / 256), cb256, 0, stream>>>(f_w1, w1f, 256, 1024);
  packW<<<dim3((256 * 1024 + 255) / 256), cb256, 0, stream>>>(h_w1, w1f + (size_t)1024 * 256, 256, 1024);
  packW<<<dim3((1024 * 1024 + 255) / 256), cb256, 0, stream>>>(f_w2, w2f, 1024, 1024);
  packW<<<dim3((1024 * 1024 + 255) / 256), cb256, 0, stream>>>(h_w2, w2f + (size_t)1024 * 1024, 1024, 1024);
  packW<<<dim3((1024 * 256 + 255) / 256), cb256, 0, stream>>>(f_w3, w3f, 1024, 256);
  packW<<<dim3((1024 * 256 + 255) / 256), cb256, 0, stream>>>(h_w3, w3f + (size_t)256 * 1024, 1024, 256);
  gpack2<<<dim3((3 * 512 * 256 * 2 + 255) / 256), cb256, 0, stream>>>(g_w1, g_b1, g_w2, gpk);

  BG g;
  // axw = ax @ WaxT + act_b  (all t, f32)
  for (int e = 0; e < E_; ++e) {
    g.A[e] = ax_bf + (size_t)e * TB_ * 192;
    g.W[e] = waxT + (size_t)e * 256 * 192;
    g.bias[e] = act_b + (size_t)e * 256;
    g.Cf[e] = axw + (size_t)e * TB_ * 256;
  }
  bgemm<128, 0, 0><<<dim3((TB_ + 127) / 128, 2, E_), 256, 0, stream>>>(g, TB_, 192, 192, 192, 256);

  // ---- Phase A: encoder + q/KL (+z0 split into zhi/zlo) ----
  for (int c = 0; c < TB_; c += CH) {
    const int rows = (TB_ - c < CH) ? (TB_ - c) : CH;
    const int mt = (rows + 127) / 128;
    for (int e = 0; e < E_; ++e) {
      g.A[e] = xs_bf + ((size_t)e * TB_ + c) * D_;
      g.W[e] = ew1T + (size_t)e * D_ * H_;
      g.bias[e] = enc_b1 + (size_t)e * H_;
      g.Cb[e] = bufA + (size_t)e * CH * H_;
    }
    bgemm<128, 1, 1><<<dim3(mt, H_ / 128, E_), 256, 0, stream>>>(g, rows, D_, D_, D_, H_);
    for (int e = 0; e < E_; ++e) {
      g.A[e] = bufA + (size_t)e * CH * H_;
      g.W[e] = ew2T + (size_t)e * H_ * H_;
      g.bias[e] = enc_b2 + (size_t)e * H_;
      g.Cb[e] = bufB + (size_t)e * CH * H_;
    }
    bgemm<128, 1, 1><<<dim3(mt, H_ / 128, E_), 256, 0, stream>>>(g, rows, H_, H_, H_, H_);
    for (int e = 0; e < E_; ++e) {
      g.A[e] = bufB + (size_t)e * CH * H_;
      g.W[e] = ew3T + (size_t)e * H_ * C_;
      g.bias[e] = enc_b3 + (size_t)e * C_;
      g.Cf[e] = bufC + (size_t)e * CH * C_;
    }
    bgemm<128, 0, 0><<<dim3(mt, C_ / 128, E_), 256, 0, stream>>>(g, rows, H_, H_, H_, C_);
    qkl_kernel<<<dim3((rows + 15) / 16, E_), 256, 0, stream>>>(
        bufC, rows, c, CH * C_, qz0_w, qz0_b, pz0_mean, pz0_logstd, eps_z0,
        zhi, zlo, logqp);
  }

  // ---- Scan: bootstrap + 2 kernels per step ----
  k1_act<<<dim3(4, 2, E_), 256, 0, stream>>>(zhi, zlo, wzh, wzl, axw, zP, zPb, 0);
  k2_l1<<<dim3(22, 16), 256, 0, stream>>>(zPb, w1f, f_b1, h_b1, fh1);
  for (int t = 0; t < T_; ++t) {
    k3_l2<<<dim3(22, 16), 256, 0, stream>>>(fh1, w2f, f_b2, h_b2, fh2);
    kfin<<<dim3(28), dim3(512), 0, stream>>>(fh2, w3f, f_b3, h_b3, gpk, g_b2,
                                             zP, dw, axw, wzh, wzl, w1f,
                                             f_b1, h_b1, zs_bf, fh1, logqp,
                                             t, (t + 1 < T_) ? 1 : 0);
  }

  // ---- Projector ----
  for (int c = 0; c < TB_; c += CH) {
    const int rows = (TB_ - c < CH) ? (TB_ - c) : CH;
    const int mt = (rows + 127) / 128;
    for (int e = 0; e < E_; ++e) {
      g.A[e] = zs_bf + ((size_t)e * T_ * B_ + c) * L_;
      g.W[e] = pw1T + (size_t)e * L_ * H_;
      g.bias[e] = proj_b1 + (size_t)e * H_;
      g.Cb[e] = bufA + (size_t)e * CH * H_;
    }
    bgemm<128, 2, 1><<<dim3(mt, H_ / 128, E_), 256, 0, stream>>>(g, rows, L_, L_, L_, H_);
    for (int e = 0; e < E_; ++e) {
      g.A[e] = bufA + (size_t)e * CH * H_;
      g.W[e] = pw2T + (size_t)e * H_ * H_;
      g.bias[e] = proj_b2 + (size_t)e * H_;
      g.Cb[e] = bufB + (size_t)e * CH * H_;
    }
    bgemm<128, 2, 1><<<dim3(mt, H_ / 128, E_), 256, 0, stream>>>(g, rows, H_, H_, H_, H_);
    for (int e = 0; e < E_; ++e) {
      g.A[e] = bufB + (size_t)e * CH * H_;
      g.W[e] = pw3T + (size_t)e * H_ * D_;
      g.bias[e] = proj_b3 + (size_t)e * D_;
      g.Cf[e] = pred + ((size_t)e * TB_ + c) * D_;
    }
    bgemm<128, 0, 0><<<dim3(mt, D_ / 128, E_), 256, 0, stream>>>(g, rows, H_, H_, H_, D_);
  }
}

// Round 13
// 11253.296 us; speedup vs baseline: 1.1460x; 1.1460x over previous
//
#include <hip/hip_runtime.h>
#include <hip/hip_bf16.h>
#include <math.h>

#define E_ 7
#define B_ 50
#define T_ 100
#define D_ 128
#define A_ 32
#define L_ 256
#define H_ 1024
#define C_ 128
#define EB_ 350
#define TB_ 5000
#define SQRTH 0.31622776601683794f

typedef __attribute__((ext_vector_type(8))) short s8v;
typedef __attribute__((ext_vector_type(4))) float f32x4;
typedef _Float16 f16x2 __attribute__((ext_vector_type(2)));
typedef __hip_bfloat16 bf16;

#define MFMA __builtin_amdgcn_mfma_f32_16x16x32_bf16

__device__ __forceinline__ int lswz(int row, int ck) {
  return (((ck & ~7) | ((ck ^ row) & 7)) << 3);
}
__device__ __forceinline__ int swzE(int r, int col) {
  const int ck = col >> 3;
  return (((ck & ~7) | ((ck ^ r) & 7)) << 3) + (col & 7);
}

struct BG {
  const bf16* A[8];
  const bf16* W[8];
  const float* bias[8];
  float* Cf[8];
  bf16* Cb[8];
};

// ---------------- bf16 MFMA GEMM (validated round 2) ----------------
template<int BM, int ACT, int OUT>
__global__ __launch_bounds__(256)
void bgemm(BG g, int M, int K, int lda, int ldw, int ldc) {
  __shared__ short As[BM * 64];
  __shared__ short Ws[128 * 64];
  const short* Ap = (const short*)g.A[blockIdx.z];
  const short* Wp = (const short*)g.W[blockIdx.z];
  const int bm = blockIdx.x * BM, bn = blockIdx.y * 128;
  const int tid = threadIdx.x;
  const int wv = tid >> 6, lane = tid & 63;
  const int wm0 = (wv >> 1) * (BM / 2), wn0 = (wv & 1) * 64;
  const int l15 = lane & 15, l4 = lane >> 4;
  constexpr int FM = BM / 32;
  constexpr int AI = BM / 32;
  f32x4 acc[FM][4] = {};
  for (int k0 = 0; k0 < K; k0 += 64) {
    s8v av[AI], wvv[4];
#pragma unroll
    for (int i = 0; i < AI; ++i) {
      const int c = tid + i * 256, r = c >> 3, ck = c & 7;
      s8v v = {};
      if (bm + r < M) v = *(const s8v*)(Ap + (size_t)(bm + r) * lda + k0 + ck * 8);
      av[i] = v;
    }
#pragma unroll
    for (int i = 0; i < 4; ++i) {
      const int c = tid + i * 256, r = c >> 3, ck = c & 7;
      wvv[i] = *(const s8v*)(Wp + (size_t)(bn + r) * ldw + k0 + ck * 8);
    }
    __syncthreads();
#pragma unroll
    for (int i = 0; i < AI; ++i) {
      const int c = tid + i * 256, r = c >> 3, ck = c & 7;
      *(s8v*)(As + r * 64 + ((ck ^ (r & 7)) << 3)) = av[i];
    }
#pragma unroll
    for (int i = 0; i < 4; ++i) {
      const int c = tid + i * 256, r = c >> 3, ck = c & 7;
      *(s8v*)(Ws + r * 64 + ((ck ^ (r & 7)) << 3)) = wvv[i];
    }
    __syncthreads();
#pragma unroll
    for (int ks = 0; ks < 2; ++ks) {
      s8v af[FM], bfr[4];
#pragma unroll
      for (int m = 0; m < FM; ++m) {
        const int r = wm0 + m * 16 + l15, ck = ks * 4 + l4;
        af[m] = *(const s8v*)(As + r * 64 + ((ck ^ (r & 7)) << 3));
      }
#pragma unroll
      for (int n = 0; n < 4; ++n) {
        const int r = wn0 + n * 16 + l15, ck = ks * 4 + l4;
        bfr[n] = *(const s8v*)(Ws + r * 64 + ((ck ^ (r & 7)) << 3));
      }
#pragma unroll
      for (int m = 0; m < FM; ++m)
#pragma unroll
        for (int n = 0; n < 4; ++n)
          acc[m][n] = MFMA(af[m], bfr[n], acc[m][n], 0, 0, 0);
    }
    __syncthreads();
  }
  const float* bias = g.bias[blockIdx.z];
  float* Cf = g.Cf[blockIdx.z];
  bf16* Cb = g.Cb[blockIdx.z];
#pragma unroll
  for (int n = 0; n < 4; ++n) {
    const int col = bn + wn0 + n * 16 + l15;
    const float bv = bias ? bias[col] : 0.f;
#pragma unroll
    for (int m = 0; m < FM; ++m) {
#pragma unroll
      for (int j = 0; j < 4; ++j) {
        const int row = bm + wm0 + m * 16 + l4 * 4 + j;
        if (row < M) {
          float v = acc[m][n][j] + bv;
          if (ACT == 1) v = fmaxf(v, 0.f);
          if (ACT == 2) v = tanhf(v);
          if (OUT == 0) Cf[(size_t)row * ldc + col] = v;
          if (OUT == 1) Cb[(size_t)row * ldc + col] = __float2bfloat16(v);
        }
      }
    }
  }
}

// ---------------- conversions / packing (validated round 6) ----------------
__global__ __launch_bounds__(256)
void cvtT_kernel(const float* __restrict__ src, bf16* __restrict__ dst,
                 int K, int N, long ss, long ds) {
  __shared__ float t[32][33];
  src += (size_t)blockIdx.z * ss;
  dst += (size_t)blockIdx.z * ds;
  const int n0 = blockIdx.x * 32, k0 = blockIdx.y * 32;
  const int tx = threadIdx.x & 31, ty = threadIdx.x >> 5;
#pragma unroll
  for (int i = 0; i < 4; ++i)
    t[ty + 8 * i][tx] = src[(size_t)(k0 + ty + 8 * i) * N + n0 + tx];
  __syncthreads();
#pragma unroll
  for (int i = 0; i < 4; ++i)
    dst[(size_t)(n0 + ty + 8 * i) * K + k0 + tx] = __float2bfloat16(t[tx][ty + 8 * i]);
}

struct B4 { bf16 a, b, c, d; };
__global__ __launch_bounds__(256)
void cvt_kernel(const float* __restrict__ s, bf16* __restrict__ d, int n4) {
  const int i = blockIdx.x * 256 + threadIdx.x;
  if (i < n4) {
    const float4 v = ((const float4*)s)[i];
    B4 o = {__float2bfloat16(v.x), __float2bfloat16(v.y),
            __float2bfloat16(v.z), __float2bfloat16(v.w)};
    ((B4*)d)[i] = o;
  }
}

__global__ __launch_bounds__(256)
void packW(const float* __restrict__ src, bf16* __restrict__ dst, int K, int N) {
  const int idx = blockIdx.x * 256 + threadIdx.x;
  if (idx >= K * N) return;
  const int k = idx / N, n = idx - k * N;
  const size_t fo = ((size_t)(n >> 4) * (K >> 5) + (k >> 5)) * 512 +
                    (((k >> 3) & 3) << 7) + ((n & 15) << 3) + (k & 7);
  dst[fo] = __float2bfloat16(src[idx]);
}

__global__ __launch_bounds__(256)
void packWz(const float* __restrict__ act_w, bf16* __restrict__ hi, bf16* __restrict__ lo) {
  const int idx = blockIdx.x * 256 + threadIdx.x;
  if (idx >= E_ * 65536) return;
  const int e = idx >> 16, rem = idx & 65535, k = rem >> 8, n = rem & 255;
  const float w = act_w[(size_t)e * 416 * 256 + (size_t)k * 256 + n];
  const bf16 h = __float2bfloat16(w);
  const size_t fo = (size_t)e * 65536 + ((size_t)(n >> 4) * 8 + (k >> 5)) * 512 +
                    (((k >> 3) & 3) << 7) + ((n & 15) << 3) + (k & 7);
  hi[fo] = h;
  lo[fo] = __float2bfloat16(w - __bfloat162float(h));
}

__global__ __launch_bounds__(256)
void ax_build(const float* __restrict__ actions, const float* __restrict__ xs,
              bf16* __restrict__ dst) {
  const int idx = blockIdx.x * 256 + threadIdx.x;
  if (idx >= E_ * TB_ * 192) return;
  const int k = idx % 192;
  const int r = (idx / 192) % TB_;
  const int e = idx / (192 * TB_);
  float v = 0.f;
  if (k < 32) v = actions[((size_t)e * TB_ + r) * A_ + k];
  else if (k < 160) v = xs[((size_t)e * TB_ + r) * D_ + (k - 32)];
  dst[idx] = __float2bfloat16(v);
}

__global__ __launch_bounds__(256)
void waxT_build(const float* __restrict__ act_w, bf16* __restrict__ dst) {
  const int idx = blockIdx.x * 256 + threadIdx.x;
  if (idx >= E_ * 256 * 192) return;
  const int k = idx % 192;
  const int n = (idx / 192) % 256;
  const int e = idx / (192 * 256);
  float v = (k < 160) ? act_w[(size_t)e * 416 * 256 + (size_t)(256 + k) * 256 + n] : 0.f;
  dst[idx] = __float2bfloat16(v);
}

__global__ __launch_bounds__(256)
void gpack_build(const float* __restrict__ gw1, const float* __restrict__ gb1,
                 const float* __restrict__ gw2, _Float16* __restrict__ dst) {
  const int idx = blockIdx.x * 256 + threadIdx.x;
  if (idx >= 256 * 3 * 1024) return;
  const int l = idx / 3072, rem = idx - l * 3072, arr = rem >> 10, h = rem & 1023;
  const float* s = arr == 0 ? gw1 : (arr == 1 ? gb1 : gw2);
  dst[idx] = (_Float16)s[(size_t)l * 1024 + h];
}

// ---------------- q/KL (+z0 split hi/lo) ----------------
__global__ __launch_bounds__(256)
void qkl_kernel(const float* __restrict__ ctx, int rows, int row_off, int ctx_estride,
                const float* __restrict__ qw, const float* __restrict__ qb,
                const float* __restrict__ pm, const float* __restrict__ pl,
                const float* __restrict__ eps0, bf16* __restrict__ z0hi,
                bf16* __restrict__ z0lo, float* __restrict__ logqp) {
  __shared__ float cx[16][128];
  __shared__ float red[16];
  const int e = blockIdx.y;
  const int r0 = blockIdx.x * 16;
  const int tid = threadIdx.x;
  {
    const int r = tid >> 4, c = (tid & 15) * 8;
    float4 v0 = make_float4(0.f, 0.f, 0.f, 0.f), v1 = v0;
    if (r0 + r < rows) {
      const float* src = ctx + (size_t)e * ctx_estride + (size_t)(r0 + r) * C_ + c;
      v0 = *(const float4*)src;
      v1 = *(const float4*)(src + 4);
    }
    *(float4*)&cx[r][c] = v0;
    *(float4*)&cx[r][c + 4] = v1;
  }
  if (tid < 16) red[tid] = 0.f;
  __syncthreads();
  const int j = tid;
  const float* w = qw + (size_t)e * C_ * 512;
  float am_[16] = {};
  float al_[16] = {};
  for (int k0 = 0; k0 < C_; k0 += 4) {
    float wm[4], wl[4];
#pragma unroll
    for (int q = 0; q < 4; ++q) {
      wm[q] = w[(size_t)(k0 + q) * 512 + j];
      wl[q] = w[(size_t)(k0 + q) * 512 + 256 + j];
    }
#pragma unroll
    for (int r = 0; r < 16; ++r) {
      const float4 cv = *(const float4*)&cx[r][k0];
      const float cc[4] = {cv.x, cv.y, cv.z, cv.w};
#pragma unroll
      for (int q = 0; q < 4; ++q) {
        am_[r] = fmaf(cc[q], wm[q], am_[r]);
        al_[r] = fmaf(cc[q], wl[q], al_[r]);
      }
    }
  }
  const float qbm = qb[(size_t)e * 512 + j];
  const float qbl = qb[(size_t)e * 512 + 256 + j];
  const float pmv = pm[(size_t)e * L_ + j];
  const float plv = pl[(size_t)e * L_ + j];
  const float inv2e = 0.5f * expf(-2.f * plv);
#pragma unroll
  for (int r = 0; r < 16; ++r) {
    float kl = 0.f;
    if (r0 + r < rows) {
      const float qm_ = am_[r] + qbm;
      const float ql_ = al_[r] + qbl;
      const float dm = qm_ - pmv;
      kl = plv - ql_ + (expf(2.f * ql_) + dm * dm) * inv2e - 0.5f;
      const int gi = row_off + r0 + r;
      if (gi < B_) {  // t == 0 rows -> z0
        const size_t zi = ((size_t)e * B_ + gi) * L_ + j;
        const float z0 = qm_ + expf(ql_) * eps0[zi];
        const bf16 h = __float2bfloat16(z0);
        z0hi[zi] = h;
        z0lo[zi] = __float2bfloat16(z0 - __bfloat162float(h));
      }
    }
    for (int off = 32; off; off >>= 1) kl += __shfl_xor(kl, off, 64);
    if ((tid & 63) == 0) atomicAdd(&red[r], kl);
  }
  __syncthreads();
  if (tid < 16 && r0 + tid < rows) atomicAdd(&logqp[e], red[tid] * (1.0f / B_));
}

// ---------------- scan slot 1: act (4x dup, wide) + L1 slice ----------------
// grid (4 q, 4 ny, 7 e) = 112 blocks, 256 thr.
// act MFMA order == round-6 k1_act; L1 order == round-6 k2_l1 -> bitwise-identical.
__global__ __launch_bounds__(256)
void s1_actl1(const bf16* __restrict__ zhi, const bf16* __restrict__ zlo,
              const bf16* __restrict__ wzh, const bf16* __restrict__ wzl,
              const float* __restrict__ axw, const bf16* __restrict__ w1f,
              const float* __restrict__ fb1, const float* __restrict__ hb1,
              float* __restrict__ zP, bf16* __restrict__ fh1, int t) {
  __shared__ short Zh[16 * 256];
  __shared__ short Zl[16 * 256];
  __shared__ short Pb[16 * 256];
  const int e = blockIdx.z, q = blockIdx.x, ny = blockIdx.y;
  const int nr = (q < 2) ? 13 : 12;
  const int b0 = (q < 2) ? q * 13 : 26 + (q - 2) * 12;
  const int R0 = e * 50 + b0;
  const int tid = threadIdx.x, lane = tid & 63, wv = tid >> 6;
  const int l15 = lane & 15, l4 = lane >> 4;
  // stage state (hi/lo) rows, swizzled
#pragma unroll
  for (int i = 0; i < 2; ++i) {
    const int lin = tid + i * 256, row = lin >> 5, ck = lin & 31;
    s8v vh = {}, vl = {};
    if (row < nr) {
      vh = *(const s8v*)((const short*)zhi + (size_t)(R0 + row) * 256 + ck * 8);
      vl = *(const s8v*)((const short*)zlo + (size_t)(R0 + row) * 256 + ck * 8);
    }
    *(s8v*)(Zh + row * 256 + lswz(row, ck)) = vh;
    *(s8v*)(Zl + row * 256 + lswz(row, ck)) = vl;
  }
  __syncthreads();
  const short* Bh = (const short*)wzh + (size_t)e * 65536;
  const short* Bl = (const short*)wzl + (size_t)e * 65536;
  // act: wave wv covers coltiles wv*4 .. wv*4+3 (all 256 cols)
#pragma unroll
  for (int c2 = 0; c2 < 4; ++c2) {
    const int ct = wv * 4 + c2;
    f32x4 acc = {};
#pragma unroll
    for (int kt = 0; kt < 8; ++kt) {
      const int ck = kt * 4 + l4;
      const s8v ah = *(const s8v*)(Zh + l15 * 256 + lswz(l15, ck));
      const s8v al = *(const s8v*)(Zl + l15 * 256 + lswz(l15, ck));
      const size_t bo = ((size_t)(ct * 8 + kt)) * 512 + (size_t)lane * 8;
      const s8v bh = *(const s8v*)(Bh + bo);
      const s8v bl = *(const s8v*)(Bl + bo);
      acc = MFMA(ah, bh, acc, 0, 0, 0);
      acc = MFMA(al, bh, acc, 0, 0, 0);
      acc = MFMA(ah, bl, acc, 0, 0, 0);
    }
    const int col = ct * 16 + l15;
#pragma unroll
    for (int j = 0; j < 4; ++j) {
      const int r = l4 * 4 + j;
      float v = 0.f;
      if (r < nr)
        v = acc[j] + axw[((size_t)e * TB_ + t * 50 + b0 + r) * 256 + col];
      *(bf16*)&Pb[r * 256 + swzE(r, col)] = __float2bfloat16(v);
      if (ny == 0 && r < nr) zP[(size_t)(R0 + r) * 256 + col] = v;
    }
  }
  __syncthreads();
  // L1 slice: global coltiles gct = ny*32 + wv*8 + c
#pragma unroll
  for (int c = 0; c < 8; ++c) {
    const int gct = ny * 32 + wv * 8 + c;
    f32x4 acc = {};
#pragma unroll
    for (int kt = 0; kt < 8; ++kt) {
      const int ck = kt * 4 + l4;
      const s8v a = *(const s8v*)(Pb + l15 * 256 + lswz(l15, ck));
      const s8v b = *(const s8v*)((const short*)w1f +
                                  ((size_t)(gct * 8 + kt)) * 512 + (size_t)lane * 8);
      acc = MFMA(a, b, acc, 0, 0, 0);
    }
    const int col = gct * 16 + l15;
    const float bv = (col < 1024) ? fb1[col] : hb1[col - 1024];
#pragma unroll
    for (int j = 0; j < 4; ++j) {
      const int r = l4 * 4 + j;
      if (r < nr)
        fh1[(size_t)(R0 + r) * 2048 + col] = __float2bfloat16(fmaxf(acc[j] + bv, 0.f));
    }
  }
}

// ---------------- scan slot 2 (round-6 k3_l2, verbatim) ----------------
__global__ __launch_bounds__(256, 2)
void k3_l2(const bf16* __restrict__ fh1, const bf16* __restrict__ w2f,
           const float* __restrict__ fb2, const float* __restrict__ hb2,
           bf16* __restrict__ fh2) {
  __shared__ short As[16 * 1024];
  const int rb = blockIdx.x, nbl = blockIdx.y;
  const int nb = nbl * 128, r0 = rb * 16;
  const int half = (nbl >= 8) ? 1024 : 0;
  const int tid = threadIdx.x, lane = tid & 63, wv = tid >> 6;
  const int l15 = lane & 15, l4 = lane >> 4;
#pragma unroll
  for (int i = 0; i < 8; ++i) {
    const int lin = tid + i * 256, row = lin >> 7, ck = lin & 127;
    s8v v = {};
    if (r0 + row < EB_)
      v = *(const s8v*)((const short*)fh1 + (size_t)(r0 + row) * 2048 + half + ck * 8);
    *(s8v*)(As + row * 1024 + lswz(row, ck)) = v;
  }
  __syncthreads();
  f32x4 acc[2] = {};
#pragma unroll 4
  for (int kt = 0; kt < 32; ++kt) {
    const int ck = kt * 4 + l4;
    const s8v a = *(const s8v*)(As + l15 * 1024 + lswz(l15, ck));
#pragma unroll
    for (int nt = 0; nt < 2; ++nt) {
      const int ng = nb + wv * 32 + nt * 16;
      const s8v b = *(const s8v*)((const short*)w2f + ((size_t)(ng >> 4) * 32 + kt) * 512 + lane * 8);
      acc[nt] = MFMA(a, b, acc[nt], 0, 0, 0);
    }
  }
#pragma unroll
  for (int nt = 0; nt < 2; ++nt) {
    const int col = nb + wv * 32 + nt * 16 + l15;
    const float bv = half ? hb2[col - 1024] : fb2[col];
#pragma unroll
    for (int j = 0; j < 4; ++j) {
      const int row = r0 + l4 * 4 + j;
      if (row < EB_)
        fh2[(size_t)row * 2048 + col] = __float2bfloat16(tanhf(acc[nt][j] + bv));
    }
  }
}

// ---------------- scan slot 3 (round-6 k4_fin, verbatim) ----------------
__global__ __launch_bounds__(256, 1)
void k4_fin(const bf16* __restrict__ fh2, const bf16* __restrict__ w3f,
            const float* __restrict__ fb3, const float* __restrict__ hb3,
            const _Float16* __restrict__ gpk, const float* __restrict__ gb2,
            const float* __restrict__ zP, const float* __restrict__ dw,
            bf16* __restrict__ zhi, bf16* __restrict__ zlo,
            bf16* __restrict__ zs_bf, float* __restrict__ logqp, int t) {
  __shared__ short As[16 * 1024];
  __shared__ float ztile[16][64];
  __shared__ float gvt[16][64];
  __shared__ float ebuck[8];
  const int rb = blockIdx.x, cb = blockIdx.y;
  const int r0 = rb * 16, c0 = cb * 64;
  const int tid = threadIdx.x, lane = tid & 63, wv = tid >> 6;
  const int l15 = lane & 15, l4 = lane >> 4;
  if (tid < 8) ebuck[tid] = 0.f;
#pragma unroll
  for (int i = 0; i < 4; ++i) {
    const int lin = tid + i * 256, row = lin >> 6, col = lin & 63;
    ztile[row][col] = (r0 + row < EB_) ? zP[(size_t)(r0 + row) * 256 + c0 + col] : 1.0f;
  }
  f32x4 accF = {}, accH = {};
#pragma unroll
  for (int fb = 0; fb < 2; ++fb) {
    __syncthreads();
#pragma unroll
    for (int i = 0; i < 8; ++i) {
      const int lin = tid + i * 256, row = lin >> 7, ck = lin & 127;
      s8v v = {};
      if (r0 + row < EB_)
        v = *(const s8v*)((const short*)fh2 + (size_t)(r0 + row) * 2048 + fb * 1024 + ck * 8);
      *(s8v*)(As + row * 1024 + lswz(row, ck)) = v;
    }
    __syncthreads();
    const int ng = fb * 256 + c0 + wv * 16;
    f32x4 acc = {};
#pragma unroll 4
    for (int kt = 0; kt < 32; ++kt) {
      const int ck = kt * 4 + l4;
      const s8v a = *(const s8v*)(As + l15 * 1024 + lswz(l15, ck));
      const s8v b = *(const s8v*)((const short*)w3f + ((size_t)(ng >> 4) * 32 + kt) * 512 + lane * 8);
      acc = MFMA(a, b, acc, 0, 0, 0);
    }
    if (fb) accH = acc; else accF = acc;
  }
  __syncthreads();
  // g-function: thread = (l_loc, quarter of h)
  {
    const int lloc = tid >> 2, hq = tid & 3;
    const _Float16* gl = gpk + (size_t)(c0 + lloc) * 3072 + hq * 256;
    f16x2 z2[16];
#pragma unroll
    for (int r = 0; r < 16; ++r) {
      const _Float16 zh_ = (_Float16)ztile[r][lloc];
      z2[r] = f16x2{zh_, zh_};
    }
    float ga[16] = {};
    for (int hp = 0; hp < 128; ++hp) {
      const f16x2 w1v = *(const f16x2*)(gl + 2 * hp);
      const f16x2 b1v = *(const f16x2*)(gl + 1024 + 2 * hp);
      const f16x2 w2v = *(const f16x2*)(gl + 2048 + 2 * hp);
#pragma unroll
      for (int r = 0; r < 16; ++r) {
        f16x2 tt = z2[r] * w1v + b1v;
#if __has_builtin(__builtin_elementwise_max)
        const f16x2 zz = {};
        tt = __builtin_elementwise_max(tt, zz);
#else
        tt[0] = tt[0] > (_Float16)0 ? tt[0] : (_Float16)0;
        tt[1] = tt[1] > (_Float16)0 ? tt[1] : (_Float16)0;
#endif
#if __has_builtin(__builtin_amdgcn_fdot2)
        ga[r] = __builtin_amdgcn_fdot2(tt, w2v, ga[r], false);
#else
        ga[r] += (float)tt[0] * (float)w2v[0] + (float)tt[1] * (float)w2v[1];
#endif
      }
    }
#pragma unroll
    for (int r = 0; r < 16; ++r) {
      float v = ga[r];
      v += __shfl_xor(v, 1, 64);
      v += __shfl_xor(v, 2, 64);
      if (hq == 0) gvt[r][lloc] = v + gb2[c0 + lloc];
    }
  }
  __syncthreads();
  // epilogue
  const int col_loc = wv * 16 + l15, col = c0 + col_loc;
  const float fb3v = fb3[col], hb3v = hb3[col];
#pragma unroll
  for (int j = 0; j < 4; ++j) {
    const int rl = l4 * 4 + j, row = r0 + rl;
    if (row < EB_) {
      const float fv = accF[j] + fb3v;
      const float hv = accH[j] + hb3v;
      const float gv = gvt[rl][col_loc];
      const float u = (fv - hv) / gv;
      atomicAdd(&ebuck[row / 50], 0.001f * u * u);
      const float znew = ztile[rl][col_loc] + 0.1f * fv +
                         gv * (SQRTH * dw[(size_t)t * (EB_ * 256) + (size_t)row * 256 + col]);
      const bf16 h = __float2bfloat16(znew);
      const size_t zi = (size_t)row * 256 + col;
      zhi[zi] = h;
      zlo[zi] = __float2bfloat16(znew - __bfloat162float(h));
      const int e = row / 50, b = row - e * 50;
      zs_bf[((size_t)e * TB_ + t * 50 + b) * 256 + col] = h;
    }
  }
  __syncthreads();
  if (tid < 7) {
    const float v = ebuck[tid];
    if (v != 0.f) atomicAdd(&logqp[tid], v);
  }
}

__global__ void init_kernel(float* logqp) {
  if (threadIdx.x < E_) logqp[threadIdx.x] = 0.f;
}

extern "C" void kernel_launch(void* const* d_in, const int* in_sizes, int n_in,
                              void* d_out, int out_size, void* d_ws, size_t ws_size,
                              hipStream_t stream) {
  (void)in_sizes; (void)n_in; (void)out_size;
  const float* enc_w1 = (const float*)d_in[0];
  const float* enc_b1 = (const float*)d_in[1];
  const float* enc_w2 = (const float*)d_in[2];
  const float* enc_b2 = (const float*)d_in[3];
  const float* enc_w3 = (const float*)d_in[4];
  const float* enc_b3 = (const float*)d_in[5];
  const float* qz0_w  = (const float*)d_in[6];
  const float* qz0_b  = (const float*)d_in[7];
  const float* act_w  = (const float*)d_in[8];
  const float* act_b  = (const float*)d_in[9];
  const float* proj_w1 = (const float*)d_in[10];
  const float* proj_b1 = (const float*)d_in[11];
  const float* proj_w2 = (const float*)d_in[12];
  const float* proj_b2 = (const float*)d_in[13];
  const float* proj_w3 = (const float*)d_in[14];
  const float* proj_b3 = (const float*)d_in[15];
  const float* f_w1 = (const float*)d_in[16];
  const float* f_b1 = (const float*)d_in[17];
  const float* f_w2 = (const float*)d_in[18];
  const float* f_b2 = (const float*)d_in[19];
  const float* f_w3 = (const float*)d_in[20];
  const float* f_b3 = (const float*)d_in[21];
  const float* h_w1 = (const float*)d_in[22];
  const float* h_b1 = (const float*)d_in[23];
  const float* h_w2 = (const float*)d_in[24];
  const float* h_b2 = (const float*)d_in[25];
  const float* h_w3 = (const float*)d_in[26];
  const float* h_b3 = (const float*)d_in[27];
  const float* g_w1 = (const float*)d_in[28];
  const float* g_b1 = (const float*)d_in[29];
  const float* g_w2 = (const float*)d_in[30];
  const float* g_b2 = (const float*)d_in[31];
  const float* pz0_mean   = (const float*)d_in[32];
  const float* pz0_logstd = (const float*)d_in[33];
  const float* xs      = (const float*)d_in[34];
  const float* actions = (const float*)d_in[35];
  const float* eps_z0  = (const float*)d_in[36];
  const float* dw      = (const float*)d_in[37];

  float* out = (float*)d_out;
  float* logqp = out;
  float* pred = out + E_;

  char* base = (char*)d_ws;
  size_t off = 0;
  auto alloc = [&](size_t bytes) {
    void* p = base + off;
    off = (off + bytes + 255) & ~(size_t)255;
    return p;
  };
  bf16* zhi    = (bf16*)alloc((size_t)EB_ * 256 * 2);
  bf16* zlo    = (bf16*)alloc((size_t)EB_ * 256 * 2);
  float* zP    = (float*)alloc((size_t)EB_ * 256 * 4);
  bf16* fh1    = (bf16*)alloc((size_t)EB_ * 2048 * 2);
  bf16* fh2    = (bf16*)alloc((size_t)EB_ * 2048 * 2);
  bf16* zs_bf  = (bf16*)alloc((size_t)E_ * T_ * B_ * 256 * 2);
  float* axw   = (float*)alloc((size_t)E_ * TB_ * 256 * 4);
  bf16* ax_bf  = (bf16*)alloc((size_t)E_ * TB_ * 192 * 2);
  bf16* waxT   = (bf16*)alloc((size_t)E_ * 256 * 192 * 2);
  bf16* wzh    = (bf16*)alloc((size_t)E_ * 65536 * 2);
  bf16* wzl    = (bf16*)alloc((size_t)E_ * 65536 * 2);
  bf16* w1f    = (bf16*)alloc((size_t)2048 * 256 * 2);
  bf16* w2f    = (bf16*)alloc((size_t)2048 * 1024 * 2);
  bf16* w3f    = (bf16*)alloc((size_t)512 * 1024 * 2);
  _Float16* gpk = (_Float16*)alloc((size_t)256 * 3 * 1024 * 2);
  bf16* xs_bf  = (bf16*)alloc((size_t)E_ * TB_ * D_ * 2);
  bf16* ew1T = (bf16*)alloc((size_t)E_ * D_ * H_ * 2);
  bf16* ew2T = (bf16*)alloc((size_t)E_ * H_ * H_ * 2);
  bf16* ew3T = (bf16*)alloc((size_t)E_ * H_ * C_ * 2);
  bf16* pw1T = (bf16*)alloc((size_t)E_ * L_ * H_ * 2);
  bf16* pw2T = (bf16*)alloc((size_t)E_ * H_ * H_ * 2);
  bf16* pw3T = (bf16*)alloc((size_t)E_ * H_ * D_ * 2);
  const size_t per_row = (size_t)E_ * (H_ * 2 * 2 + C_ * 4);
  size_t remain = (ws_size > off + 4096) ? (ws_size - off - 4096) : 0;
  int CH = (int)(remain / per_row);
  if (CH > 2500) CH = 2500;
  if (CH < 64) CH = 64;
  bf16* bufA = (bf16*)alloc((size_t)E_ * CH * H_ * 2);
  bf16* bufB = (bf16*)alloc((size_t)E_ * CH * H_ * 2);
  float* bufC = (float*)alloc((size_t)E_ * CH * C_ * 4);

  init_kernel<<<dim3(1), dim3(64), 0, stream>>>(logqp);

  const dim3 cb256(256);
  cvt_kernel<<<dim3((E_ * TB_ * D_ / 4 + 255) / 256), cb256, 0, stream>>>(xs, xs_bf, E_ * TB_ * D_ / 4);
  cvtT_kernel<<<dim3(H_ / 32, D_ / 32, E_), cb256, 0, stream>>>(enc_w1, ew1T, D_, H_, (long)D_ * H_, (long)D_ * H_);
  cvtT_kernel<<<dim3(H_ / 32, H_ / 32, E_), cb256, 0, stream>>>(enc_w2, ew2T, H_, H_, (long)H_ * H_, (long)H_ * H_);
  cvtT_kernel<<<dim3(C_ / 32, H_ / 32, E_), cb256, 0, stream>>>(enc_w3, ew3T, H_, C_, (long)H_ * C_, (long)H_ * C_);
  cvtT_kernel<<<dim3(H_ / 32, L_ / 32, E_), cb256, 0, stream>>>(proj_w1, pw1T, L_, H_, (long)L_ * H_, (long)L_ * H_);
  cvtT_kernel<<<dim3(H_ / 32, H_ / 32, E_), cb256, 0, stream>>>(proj_w2, pw2T, H_, H_, (long)H_ * H_, (long)H_ * H_);
  cvtT_kernel<<<dim3(D_ / 32, H_ / 32, E_), cb256, 0, stream>>>(proj_w3, pw3T, H_, D_, (long)H_ * D_, (long)H_ * D_);
  ax_build<<<dim3((E_ * TB_ * 192 + 255) / 256), cb256, 0, stream>>>(actions, xs, ax_bf);
  waxT_build<<<dim3((E_ * 256 * 192 + 255) / 256), cb256, 0, stream>>>(act_w, waxT);
  packWz<<<dim3((E_ * 65536 + 255) / 256), cb256, 0, stream>>>(act_w, wzh, wzl);
  packW<<<dim3((256 * 1024 + 255) / 256), cb256, 0, stream>>>(f_w1, w1f, 256, 1024);
  packW<<<dim3((256 * 1024 + 255) / 256), cb256, 0, stream>>>(h_w1, w1f + (size_t)1024 * 256, 256, 1024);
  packW<<<dim3((1024 * 1024 + 255) / 256), cb256, 0, stream>>>(f_w2, w2f, 1024, 1024);
  packW<<<dim3((1024 * 1024 + 255) / 256), cb256, 0, stream>>>(h_w2, w2f + (size_t)1024 * 1024, 1024, 1024);
  packW<<<dim3((1024 * 256 + 255) / 256), cb256, 0, stream>>>(f_w3, w3f, 1024, 256);
  packW<<<dim3((1024 * 256 + 255) / 256), cb256, 0, stream>>>(h_w3, w3f + (size_t)256 * 1024, 1024, 256);
  gpack_build<<<dim3((256 * 3 * 1024 + 255) / 256), cb256, 0, stream>>>(g_w1, g_b1, g_w2, gpk);

  BG g;
  // axw = ax @ WaxT + act_b  (all t, f32)
  for (int e = 0; e < E_; ++e) {
    g.A[e] = ax_bf + (size_t)e * TB_ * 192;
    g.W[e] = waxT + (size_t)e * 256 * 192;
    g.bias[e] = act_b + (size_t)e * 256;
    g.Cf[e] = axw + (size_t)e * TB_ * 256;
  }
  bgemm<128, 0, 0><<<dim3((TB_ + 127) / 128, 2, E_), 256, 0, stream>>>(g, TB_, 192, 192, 192, 256);

  // ---- Phase A: encoder + q/KL (+z0 split into zhi/zlo) ----
  for (int c = 0; c < TB_; c += CH) {
    const int rows = (TB_ - c < CH) ? (TB_ - c) : CH;
    const int mt = (rows + 127) / 128;
    for (int e = 0; e < E_; ++e) {
      g.A[e] = xs_bf + ((size_t)e * TB_ + c) * D_;
      g.W[e] = ew1T + (size_t)e * D_ * H_;
      g.bias[e] = enc_b1 + (size_t)e * H_;
      g.Cb[e] = bufA + (size_t)e * CH * H_;
    }
    bgemm<128, 1, 1><<<dim3(mt, H_ / 128, E_), 256, 0, stream>>>(g, rows, D_, D_, D_, H_);
    for (int e = 0; e < E_; ++e) {
      g.A[e] = bufA + (size_t)e * CH * H_;
      g.W[e] = ew2T + (size_t)e * H_ * H_;
      g.bias[e] = enc_b2 + (size_t)e * H_;
      g.Cb[e] = bufB + (size_t)e * CH * H_;
    }
    bgemm<128, 1, 1><<<dim3(mt, H_ / 128, E_), 256, 0, stream>>>(g, rows, H_, H_, H_, H_);
    for (int e = 0; e < E_; ++e) {
      g.A[e] = bufB + (size_t)e * CH * H_;
      g.W[e] = ew3T + (size_t)e * H_ * C_;
      g.bias[e] = enc_b3 + (size_t)e * C_;
      g.Cf[e] = bufC + (size_t)e * CH * C_;
    }
    bgemm<128, 0, 0><<<dim3(mt, C_ / 128, E_), 256, 0, stream>>>(g, rows, H_, H_, H_, C_);
    qkl_kernel<<<dim3((rows + 15) / 16, E_), 256, 0, stream>>>(
        bufC, rows, c, CH * C_, qz0_w, qz0_b, pz0_mean, pz0_logstd, eps_z0,
        zhi, zlo, logqp);
  }

  // ---- Scan: 3 kernels per step ----
  for (int t = 0; t < T_; ++t) {
    s1_actl1<<<dim3(4, 4, E_), 256, 0, stream>>>(zhi, zlo, wzh, wzl, axw, w1f,
                                                 f_b1, h_b1, zP, fh1, t);
    k3_l2<<<dim3(22, 16), 256, 0, stream>>>(fh1, w2f, f_b2, h_b2, fh2);
    k4_fin<<<dim3(22, 4), 256, 0, stream>>>(fh2, w3f, f_b3, h_b3, gpk, g_b2,
                                            zP, dw, zhi, zlo, zs_bf, logqp, t);
  }

  // ---- Projector ----
  for (int c = 0; c < TB_; c += CH) {
    const int rows = (TB_ - c < CH) ? (TB_ - c) : CH;
    const int mt = (rows + 127) / 128;
    for (int e = 0; e < E_; ++e) {
      g.A[e] = zs_bf + ((size_t)e * T_ * B_ + c) * L_;
      g.W[e] = pw1T + (size_t)e * L_ * H_;
      g.bias[e] = proj_b1 + (size_t)e * H_;
      g.Cb[e] = bufA + (size_t)e * CH * H_;
    }
    bgemm<128, 2, 1><<<dim3(mt, H_ / 128, E_), 256, 0, stream>>>(g, rows, L_, L_, L_, H_);
    for (int e = 0; e < E_; ++e) {
      g.A[e] = bufA + (size_t)e * CH * H_;
      g.W[e] = pw2T + (size_t)e * H_ * H_;
      g.bias[e] = proj_b2 + (size_t)e * H_;
      g.Cb[e] = bufB + (size_t)e * CH * H_;
    }
    bgemm<128, 2, 1><<<dim3(mt, H_ / 128, E_), 256, 0, stream>>>(g, rows, H_, H_, H_, H_);
    for (int e = 0; e < E_; ++e) {
      g.A[e] = bufB + (size_t)e * CH * H_;
      g.W[e] = pw3T + (size_t)e * H_ * D_;
      g.bias[e] = proj_b3 + (size_t)e * D_;
      g.Cf[e] = pred + ((size_t)e * TB_ + c) * D_;
    }
    bgemm<128, 0, 0><<<dim3(mt, D_ / 128, E_), 256, 0, stream>>>(g, rows, H_, H_, H_, D_);
  }
}

// Round 14
// 9914.590 us; speedup vs baseline: 1.3007x; 1.1350x over previous
//
#include <hip/hip_runtime.h>
#include <hip/hip_bf16.h>
#include <math.h>

#define E_ 7
#define B_ 50
#define T_ 100
#define D_ 128
#define A_ 32
#define L_ 256
#define H_ 1024
#define C_ 128
#define EB_ 350
#define TB_ 5000
#define SQRTH 0.31622776601683794f

typedef __attribute__((ext_vector_type(8))) short s8v;
typedef __attribute__((ext_vector_type(4))) float f32x4;
typedef _Float16 f16x2 __attribute__((ext_vector_type(2)));
typedef __hip_bfloat16 bf16;

#define MFMA __builtin_amdgcn_mfma_f32_16x16x32_bf16

__device__ __forceinline__ int lswz(int row, int ck) {
  return (((ck & ~7) | ((ck ^ row) & 7)) << 3);
}
__device__ __forceinline__ int swzE(int r, int col) {
  const int ck = col >> 3;
  return (((ck & ~7) | ((ck ^ r) & 7)) << 3) + (col & 7);
}

struct BG {
  const bf16* A[8];
  const bf16* W[8];
  const float* bias[8];
  float* Cf[8];
  bf16* Cb[8];
};

// ---------------- bf16 MFMA GEMM (validated round 2) ----------------
template<int BM, int ACT, int OUT>
__global__ __launch_bounds__(256)
void bgemm(BG g, int M, int K, int lda, int ldw, int ldc) {
  __shared__ short As[BM * 64];
  __shared__ short Ws[128 * 64];
  const short* Ap = (const short*)g.A[blockIdx.z];
  const short* Wp = (const short*)g.W[blockIdx.z];
  const int bm = blockIdx.x * BM, bn = blockIdx.y * 128;
  const int tid = threadIdx.x;
  const int wv = tid >> 6, lane = tid & 63;
  const int wm0 = (wv >> 1) * (BM / 2), wn0 = (wv & 1) * 64;
  const int l15 = lane & 15, l4 = lane >> 4;
  constexpr int FM = BM / 32;
  constexpr int AI = BM / 32;
  f32x4 acc[FM][4] = {};
  for (int k0 = 0; k0 < K; k0 += 64) {
    s8v av[AI], wvv[4];
#pragma unroll
    for (int i = 0; i < AI; ++i) {
      const int c = tid + i * 256, r = c >> 3, ck = c & 7;
      s8v v = {};
      if (bm + r < M) v = *(const s8v*)(Ap + (size_t)(bm + r) * lda + k0 + ck * 8);
      av[i] = v;
    }
#pragma unroll
    for (int i = 0; i < 4; ++i) {
      const int c = tid + i * 256, r = c >> 3, ck = c & 7;
      wvv[i] = *(const s8v*)(Wp + (size_t)(bn + r) * ldw + k0 + ck * 8);
    }
    __syncthreads();
#pragma unroll
    for (int i = 0; i < AI; ++i) {
      const int c = tid + i * 256, r = c >> 3, ck = c & 7;
      *(s8v*)(As + r * 64 + ((ck ^ (r & 7)) << 3)) = av[i];
    }
#pragma unroll
    for (int i = 0; i < 4; ++i) {
      const int c = tid + i * 256, r = c >> 3, ck = c & 7;
      *(s8v*)(Ws + r * 64 + ((ck ^ (r & 7)) << 3)) = wvv[i];
    }
    __syncthreads();
#pragma unroll
    for (int ks = 0; ks < 2; ++ks) {
      s8v af[FM], bfr[4];
#pragma unroll
      for (int m = 0; m < FM; ++m) {
        const int r = wm0 + m * 16 + l15, ck = ks * 4 + l4;
        af[m] = *(const s8v*)(As + r * 64 + ((ck ^ (r & 7)) << 3));
      }
#pragma unroll
      for (int n = 0; n < 4; ++n) {
        const int r = wn0 + n * 16 + l15, ck = ks * 4 + l4;
        bfr[n] = *(const s8v*)(Ws + r * 64 + ((ck ^ (r & 7)) << 3));
      }
#pragma unroll
      for (int m = 0; m < FM; ++m)
#pragma unroll
        for (int n = 0; n < 4; ++n)
          acc[m][n] = MFMA(af[m], bfr[n], acc[m][n], 0, 0, 0);
    }
    __syncthreads();
  }
  const float* bias = g.bias[blockIdx.z];
  float* Cf = g.Cf[blockIdx.z];
  bf16* Cb = g.Cb[blockIdx.z];
#pragma unroll
  for (int n = 0; n < 4; ++n) {
    const int col = bn + wn0 + n * 16 + l15;
    const float bv = bias ? bias[col] : 0.f;
#pragma unroll
    for (int m = 0; m < FM; ++m) {
#pragma unroll
      for (int j = 0; j < 4; ++j) {
        const int row = bm + wm0 + m * 16 + l4 * 4 + j;
        if (row < M) {
          float v = acc[m][n][j] + bv;
          if (ACT == 1) v = fmaxf(v, 0.f);
          if (ACT == 2) v = tanhf(v);
          if (OUT == 0) Cf[(size_t)row * ldc + col] = v;
          if (OUT == 1) Cb[(size_t)row * ldc + col] = __float2bfloat16(v);
        }
      }
    }
  }
}

// ---------------- conversions / packing (validated round 6) ----------------
__global__ __launch_bounds__(256)
void cvtT_kernel(const float* __restrict__ src, bf16* __restrict__ dst,
                 int K, int N, long ss, long ds) {
  __shared__ float t[32][33];
  src += (size_t)blockIdx.z * ss;
  dst += (size_t)blockIdx.z * ds;
  const int n0 = blockIdx.x * 32, k0 = blockIdx.y * 32;
  const int tx = threadIdx.x & 31, ty = threadIdx.x >> 5;
#pragma unroll
  for (int i = 0; i < 4; ++i)
    t[ty + 8 * i][tx] = src[(size_t)(k0 + ty + 8 * i) * N + n0 + tx];
  __syncthreads();
#pragma unroll
  for (int i = 0; i < 4; ++i)
    dst[(size_t)(n0 + ty + 8 * i) * K + k0 + tx] = __float2bfloat16(t[tx][ty + 8 * i]);
}

struct B4 { bf16 a, b, c, d; };
__global__ __launch_bounds__(256)
void cvt_kernel(const float* __restrict__ s, bf16* __restrict__ d, int n4) {
  const int i = blockIdx.x * 256 + threadIdx.x;
  if (i < n4) {
    const float4 v = ((const float4*)s)[i];
    B4 o = {__float2bfloat16(v.x), __float2bfloat16(v.y),
            __float2bfloat16(v.z), __float2bfloat16(v.w)};
    ((B4*)d)[i] = o;
  }
}

__global__ __launch_bounds__(256)
void packW(const float* __restrict__ src, bf16* __restrict__ dst, int K, int N) {
  const int idx = blockIdx.x * 256 + threadIdx.x;
  if (idx >= K * N) return;
  const int k = idx / N, n = idx - k * N;
  const size_t fo = ((size_t)(n >> 4) * (K >> 5) + (k >> 5)) * 512 +
                    (((k >> 3) & 3) << 7) + ((n & 15) << 3) + (k & 7);
  dst[fo] = __float2bfloat16(src[idx]);
}

__global__ __launch_bounds__(256)
void packWz(const float* __restrict__ act_w, bf16* __restrict__ hi, bf16* __restrict__ lo) {
  const int idx = blockIdx.x * 256 + threadIdx.x;
  if (idx >= E_ * 65536) return;
  const int e = idx >> 16, rem = idx & 65535, k = rem >> 8, n = rem & 255;
  const float w = act_w[(size_t)e * 416 * 256 + (size_t)k * 256 + n];
  const bf16 h = __float2bfloat16(w);
  const size_t fo = (size_t)e * 65536 + ((size_t)(n >> 4) * 8 + (k >> 5)) * 512 +
                    (((k >> 3) & 3) << 7) + ((n & 15) << 3) + (k & 7);
  hi[fo] = h;
  lo[fo] = __float2bfloat16(w - __bfloat162float(h));
}

__global__ __launch_bounds__(256)
void ax_build(const float* __restrict__ actions, const float* __restrict__ xs,
              bf16* __restrict__ dst) {
  const int idx = blockIdx.x * 256 + threadIdx.x;
  if (idx >= E_ * TB_ * 192) return;
  const int k = idx % 192;
  const int r = (idx / 192) % TB_;
  const int e = idx / (192 * TB_);
  float v = 0.f;
  if (k < 32) v = actions[((size_t)e * TB_ + r) * A_ + k];
  else if (k < 160) v = xs[((size_t)e * TB_ + r) * D_ + (k - 32)];
  dst[idx] = __float2bfloat16(v);
}

__global__ __launch_bounds__(256)
void waxT_build(const float* __restrict__ act_w, bf16* __restrict__ dst) {
  const int idx = blockIdx.x * 256 + threadIdx.x;
  if (idx >= E_ * 256 * 192) return;
  const int k = idx % 192;
  const int n = (idx / 192) % 256;
  const int e = idx / (192 * 256);
  float v = (k < 160) ? act_w[(size_t)e * 416 * 256 + (size_t)(256 + k) * 256 + n] : 0.f;
  dst[idx] = __float2bfloat16(v);
}

__global__ __launch_bounds__(256)
void gpack_build(const float* __restrict__ gw1, const float* __restrict__ gb1,
                 const float* __restrict__ gw2, _Float16* __restrict__ dst) {
  const int idx = blockIdx.x * 256 + threadIdx.x;
  if (idx >= 256 * 3 * 1024) return;
  const int l = idx / 3072, rem = idx - l * 3072, arr = rem >> 10, h = rem & 1023;
  const float* s = arr == 0 ? gw1 : (arr == 1 ? gb1 : gw2);
  dst[idx] = (_Float16)s[(size_t)l * 1024 + h];
}

// ---------------- q/KL (+z0 split hi/lo) ----------------
__global__ __launch_bounds__(256)
void qkl_kernel(const float* __restrict__ ctx, int rows, int row_off, int ctx_estride,
                const float* __restrict__ qw, const float* __restrict__ qb,
                const float* __restrict__ pm, const float* __restrict__ pl,
                const float* __restrict__ eps0, bf16* __restrict__ z0hi,
                bf16* __restrict__ z0lo, float* __restrict__ logqp) {
  __shared__ float cx[16][128];
  __shared__ float red[16];
  const int e = blockIdx.y;
  const int r0 = blockIdx.x * 16;
  const int tid = threadIdx.x;
  {
    const int r = tid >> 4, c = (tid & 15) * 8;
    float4 v0 = make_float4(0.f, 0.f, 0.f, 0.f), v1 = v0;
    if (r0 + r < rows) {
      const float* src = ctx + (size_t)e * ctx_estride + (size_t)(r0 + r) * C_ + c;
      v0 = *(const float4*)src;
      v1 = *(const float4*)(src + 4);
    }
    *(float4*)&cx[r][c] = v0;
    *(float4*)&cx[r][c + 4] = v1;
  }
  if (tid < 16) red[tid] = 0.f;
  __syncthreads();
  const int j = tid;
  const float* w = qw + (size_t)e * C_ * 512;
  float am_[16] = {};
  float al_[16] = {};
  for (int k0 = 0; k0 < C_; k0 += 4) {
    float wm[4], wl[4];
#pragma unroll
    for (int q = 0; q < 4; ++q) {
      wm[q] = w[(size_t)(k0 + q) * 512 + j];
      wl[q] = w[(size_t)(k0 + q) * 512 + 256 + j];
    }
#pragma unroll
    for (int r = 0; r < 16; ++r) {
      const float4 cv = *(const float4*)&cx[r][k0];
      const float cc[4] = {cv.x, cv.y, cv.z, cv.w};
#pragma unroll
      for (int q = 0; q < 4; ++q) {
        am_[r] = fmaf(cc[q], wm[q], am_[r]);
        al_[r] = fmaf(cc[q], wl[q], al_[r]);
      }
    }
  }
  const float qbm = qb[(size_t)e * 512 + j];
  const float qbl = qb[(size_t)e * 512 + 256 + j];
  const float pmv = pm[(size_t)e * L_ + j];
  const float plv = pl[(size_t)e * L_ + j];
  const float inv2e = 0.5f * expf(-2.f * plv);
#pragma unroll
  for (int r = 0; r < 16; ++r) {
    float kl = 0.f;
    if (r0 + r < rows) {
      const float qm_ = am_[r] + qbm;
      const float ql_ = al_[r] + qbl;
      const float dm = qm_ - pmv;
      kl = plv - ql_ + (expf(2.f * ql_) + dm * dm) * inv2e - 0.5f;
      const int gi = row_off + r0 + r;
      if (gi < B_) {  // t == 0 rows -> z0
        const size_t zi = ((size_t)e * B_ + gi) * L_ + j;
        const float z0 = qm_ + expf(ql_) * eps0[zi];
        const bf16 h = __float2bfloat16(z0);
        z0hi[zi] = h;
        z0lo[zi] = __float2bfloat16(z0 - __bfloat162float(h));
      }
    }
    for (int off = 32; off; off >>= 1) kl += __shfl_xor(kl, off, 64);
    if ((tid & 63) == 0) atomicAdd(&red[r], kl);
  }
  __syncthreads();
  if (tid < 16 && r0 + tid < rows) atomicAdd(&logqp[e], red[tid] * (1.0f / B_));
}

// ---------------- scan step kernels ----------------
// K1: zP = (zhi+zlo) @ Wz(hi/lo) + axw[t].  grid (4 rb13, 2 nt128, 7 e)
__global__ __launch_bounds__(256, 2)
void k1_act(const bf16* __restrict__ zhi, const bf16* __restrict__ zlo,
            const bf16* __restrict__ wzh, const bf16* __restrict__ wzl,
            const float* __restrict__ axw, float* __restrict__ zP,
            bf16* __restrict__ zPb, int t) {
  __shared__ short Ah[16 * 256];
  __shared__ short Al[16 * 256];
  const int e = blockIdx.z, rb = blockIdx.x, nb = blockIdx.y * 128;
  const int r0 = rb * 13;
  const int nrows = (50 - r0 < 13) ? (50 - r0) : 13;
  const int tid = threadIdx.x, lane = tid & 63, wv = tid >> 6;
  const int l15 = lane & 15, l4 = lane >> 4;
  const short* zh = (const short*)zhi + (size_t)(e * 50 + r0) * 256;
  const short* zl = (const short*)zlo + (size_t)(e * 50 + r0) * 256;
#pragma unroll
  for (int i = 0; i < 2; ++i) {
    const int lin = tid + i * 256, row = lin >> 5, ck = lin & 31;
    s8v vh = {}, vl = {};
    if (row < nrows) {
      vh = *(const s8v*)(zh + row * 256 + ck * 8);
      vl = *(const s8v*)(zl + row * 256 + ck * 8);
    }
    *(s8v*)(Ah + row * 256 + lswz(row, ck)) = vh;
    *(s8v*)(Al + row * 256 + lswz(row, ck)) = vl;
  }
  __syncthreads();
  const short* Bh = (const short*)wzh + (size_t)e * 65536;
  const short* Bl = (const short*)wzl + (size_t)e * 65536;
  f32x4 acc[2] = {};
#pragma unroll
  for (int kt = 0; kt < 8; ++kt) {
    const int ck = kt * 4 + l4;
    const s8v ah = *(const s8v*)(Ah + l15 * 256 + lswz(l15, ck));
    const s8v al = *(const s8v*)(Al + l15 * 256 + lswz(l15, ck));
#pragma unroll
    for (int nt = 0; nt < 2; ++nt) {
      const int ng = nb + wv * 32 + nt * 16;
      const size_t bo = ((size_t)(ng >> 4) * 8 + kt) * 512 + lane * 8;
      const s8v bh = *(const s8v*)(Bh + bo);
      const s8v bl = *(const s8v*)(Bl + bo);
      acc[nt] = MFMA(ah, bh, acc[nt], 0, 0, 0);
      acc[nt] = MFMA(al, bh, acc[nt], 0, 0, 0);
      acc[nt] = MFMA(ah, bl, acc[nt], 0, 0, 0);
    }
  }
#pragma unroll
  for (int nt = 0; nt < 2; ++nt) {
    const int col = nb + wv * 32 + nt * 16 + l15;
#pragma unroll
    for (int j = 0; j < 4; ++j) {
      const int row = l4 * 4 + j;
      if (row < nrows) {
        const int gr = e * 50 + r0 + row;
        const float v = acc[nt][j] + axw[((size_t)e * TB_ + t * 50 + r0 + row) * 256 + col];
        zP[(size_t)gr * 256 + col] = v;
        zPb[(size_t)gr * 256 + col] = __float2bfloat16(v);
      }
    }
  }
}

// K2: fh1 = relu(zPb @ W1fh + b1).  grid (22 rb16, 16 nt128)
__global__ __launch_bounds__(256, 2)
void k2_l1(const bf16* __restrict__ zPb, const bf16* __restrict__ w1f,
           const float* __restrict__ fb1, const float* __restrict__ hb1,
           bf16* __restrict__ fh1) {
  __shared__ short As[16 * 256];
  const int rb = blockIdx.x, nb = blockIdx.y * 128;
  const int r0 = rb * 16;
  const int tid = threadIdx.x, lane = tid & 63, wv = tid >> 6;
  const int l15 = lane & 15, l4 = lane >> 4;
#pragma unroll
  for (int i = 0; i < 2; ++i) {
    const int lin = tid + i * 256, row = lin >> 5, ck = lin & 31;
    s8v v = {};
    if (r0 + row < EB_)
      v = *(const s8v*)((const short*)zPb + (size_t)(r0 + row) * 256 + ck * 8);
    *(s8v*)(As + row * 256 + lswz(row, ck)) = v;
  }
  __syncthreads();
  f32x4 acc[2] = {};
#pragma unroll
  for (int kt = 0; kt < 8; ++kt) {
    const int ck = kt * 4 + l4;
    const s8v a = *(const s8v*)(As + l15 * 256 + lswz(l15, ck));
#pragma unroll
    for (int nt = 0; nt < 2; ++nt) {
      const int ng = nb + wv * 32 + nt * 16;
      const s8v b = *(const s8v*)((const short*)w1f + ((size_t)(ng >> 4) * 8 + kt) * 512 + lane * 8);
      acc[nt] = MFMA(a, b, acc[nt], 0, 0, 0);
    }
  }
#pragma unroll
  for (int nt = 0; nt < 2; ++nt) {
    const int col = nb + wv * 32 + nt * 16 + l15;
    const float bv = (col < 1024) ? fb1[col] : hb1[col - 1024];
#pragma unroll
    for (int j = 0; j < 4; ++j) {
      const int row = r0 + l4 * 4 + j;
      if (row < EB_)
        fh1[(size_t)row * 2048 + col] = __float2bfloat16(fmaxf(acc[nt][j] + bv, 0.f));
    }
  }
}

// K3+G: y<16 -> fh2 = tanh(fh1 @ W2 + b2); y>=16 -> g-function -> gv (global).
// grid (22 rb16, 20)
__global__ __launch_bounds__(256, 2)
void k3g(const bf16* __restrict__ fh1, const bf16* __restrict__ w2f,
         const float* __restrict__ fb2, const float* __restrict__ hb2,
         bf16* __restrict__ fh2, const float* __restrict__ zP,
         const _Float16* __restrict__ gpk, const float* __restrict__ gb2,
         float* __restrict__ gv) {
  __shared__ short As[16 * 1024];
  const int rb = blockIdx.x, nbl = blockIdx.y;
  const int tid = threadIdx.x, lane = tid & 63, wv = tid >> 6;
  const int l15 = lane & 15, l4 = lane >> 4;
  const int r0 = rb * 16;
  if (nbl >= 16) {
    // ---- g block: rows r0..r0+15, l-cols c0..c0+63 (code = round-6 k4_fin g) ----
    float* ztile = (float*)As;  // reuse LDS: 16x64 f32
    const int c0 = (nbl - 16) * 64;
#pragma unroll
    for (int i = 0; i < 4; ++i) {
      const int lin = tid + i * 256, row = lin >> 6, col = lin & 63;
      ztile[row * 64 + col] =
          (r0 + row < EB_) ? zP[(size_t)(r0 + row) * 256 + c0 + col] : 1.0f;
    }
    __syncthreads();
    const int lloc = tid >> 2, hq = tid & 3;
    const _Float16* gl = gpk + (size_t)(c0 + lloc) * 3072 + hq * 256;
    f16x2 z2[16];
#pragma unroll
    for (int r = 0; r < 16; ++r) {
      const _Float16 zh_ = (_Float16)ztile[r * 64 + lloc];
      z2[r] = f16x2{zh_, zh_};
    }
    float ga[16] = {};
    for (int hp = 0; hp < 128; ++hp) {
      const f16x2 w1v = *(const f16x2*)(gl + 2 * hp);
      const f16x2 b1v = *(const f16x2*)(gl + 1024 + 2 * hp);
      const f16x2 w2v = *(const f16x2*)(gl + 2048 + 2 * hp);
#pragma unroll
      for (int r = 0; r < 16; ++r) {
        f16x2 tt = z2[r] * w1v + b1v;
#if __has_builtin(__builtin_elementwise_max)
        const f16x2 zz = {};
        tt = __builtin_elementwise_max(tt, zz);
#else
        tt[0] = tt[0] > (_Float16)0 ? tt[0] : (_Float16)0;
        tt[1] = tt[1] > (_Float16)0 ? tt[1] : (_Float16)0;
#endif
#if __has_builtin(__builtin_amdgcn_fdot2)
        ga[r] = __builtin_amdgcn_fdot2(tt, w2v, ga[r], false);
#else
        ga[r] += (float)tt[0] * (float)w2v[0] + (float)tt[1] * (float)w2v[1];
#endif
      }
    }
#pragma unroll
    for (int r = 0; r < 16; ++r) {
      float v = ga[r];
      v += __shfl_xor(v, 1, 64);
      v += __shfl_xor(v, 2, 64);
      if (hq == 0 && r0 + r < EB_)
        gv[(size_t)(r0 + r) * 256 + c0 + lloc] = v + gb2[c0 + lloc];
    }
    return;
  }
  // ---- L2 block (round-6 k3_l2 verbatim) ----
  const int nb = nbl * 128;
  const int half = (nbl >= 8) ? 1024 : 0;
#pragma unroll
  for (int i = 0; i < 8; ++i) {
    const int lin = tid + i * 256, row = lin >> 7, ck = lin & 127;
    s8v v = {};
    if (r0 + row < EB_)
      v = *(const s8v*)((const short*)fh1 + (size_t)(r0 + row) * 2048 + half + ck * 8);
    *(s8v*)(As + row * 1024 + lswz(row, ck)) = v;
  }
  __syncthreads();
  f32x4 acc[2] = {};
#pragma unroll 4
  for (int kt = 0; kt < 32; ++kt) {
    const int ck = kt * 4 + l4;
    const s8v a = *(const s8v*)(As + l15 * 1024 + lswz(l15, ck));
#pragma unroll
    for (int nt = 0; nt < 2; ++nt) {
      const int ng = nb + wv * 32 + nt * 16;
      const s8v b = *(const s8v*)((const short*)w2f + ((size_t)(ng >> 4) * 32 + kt) * 512 + lane * 8);
      acc[nt] = MFMA(a, b, acc[nt], 0, 0, 0);
    }
  }
#pragma unroll
  for (int nt = 0; nt < 2; ++nt) {
    const int col = nb + wv * 32 + nt * 16 + l15;
    const float bv = half ? hb2[col - 1024] : fb2[col];
#pragma unroll
    for (int j = 0; j < 4; ++j) {
      const int row = r0 + l4 * 4 + j;
      if (row < EB_)
        fh2[(size_t)row * 2048 + col] = __float2bfloat16(tanhf(acc[nt][j] + bv));
    }
  }
}

// K4: fv/hv GEMMs + epilogue (g read from gv).  grid (22 rb16, 4 cb64)
__global__ __launch_bounds__(256, 1)
void k4_fin(const bf16* __restrict__ fh2, const bf16* __restrict__ w3f,
            const float* __restrict__ fb3, const float* __restrict__ hb3,
            const float* __restrict__ gv, const float* __restrict__ zP,
            const float* __restrict__ dw, bf16* __restrict__ zhi,
            bf16* __restrict__ zlo, bf16* __restrict__ zs_bf,
            float* __restrict__ logqp, int t) {
  __shared__ short As[16 * 1024];
  __shared__ float ztile[16][64];
  __shared__ float ebuck[8];
  const int rb = blockIdx.x, cb = blockIdx.y;
  const int r0 = rb * 16, c0 = cb * 64;
  const int tid = threadIdx.x, lane = tid & 63, wv = tid >> 6;
  const int l15 = lane & 15, l4 = lane >> 4;
  if (tid < 8) ebuck[tid] = 0.f;
#pragma unroll
  for (int i = 0; i < 4; ++i) {
    const int lin = tid + i * 256, row = lin >> 6, col = lin & 63;
    ztile[row][col] = (r0 + row < EB_) ? zP[(size_t)(r0 + row) * 256 + c0 + col] : 1.0f;
  }
  f32x4 accF = {}, accH = {};
#pragma unroll
  for (int fb = 0; fb < 2; ++fb) {
    __syncthreads();
#pragma unroll
    for (int i = 0; i < 8; ++i) {
      const int lin = tid + i * 256, row = lin >> 7, ck = lin & 127;
      s8v v = {};
      if (r0 + row < EB_)
        v = *(const s8v*)((const short*)fh2 + (size_t)(r0 + row) * 2048 + fb * 1024 + ck * 8);
      *(s8v*)(As + row * 1024 + lswz(row, ck)) = v;
    }
    __syncthreads();
    const int ng = fb * 256 + c0 + wv * 16;
    f32x4 acc = {};
#pragma unroll 4
    for (int kt = 0; kt < 32; ++kt) {
      const int ck = kt * 4 + l4;
      const s8v a = *(const s8v*)(As + l15 * 1024 + lswz(l15, ck));
      const s8v b = *(const s8v*)((const short*)w3f + ((size_t)(ng >> 4) * 32 + kt) * 512 + lane * 8);
      acc = MFMA(a, b, acc, 0, 0, 0);
    }
    if (fb) accH = acc; else accF = acc;
  }
  __syncthreads();
  // epilogue (g read from global gv — values bitwise identical to round 6)
  const int col_loc = wv * 16 + l15, col = c0 + col_loc;
  const float fb3v = fb3[col], hb3v = hb3[col];
#pragma unroll
  for (int j = 0; j < 4; ++j) {
    const int rl = l4 * 4 + j, row = r0 + rl;
    if (row < EB_) {
      const float fv = accF[j] + fb3v;
      const float hv = accH[j] + hb3v;
      const float gvv = gv[(size_t)row * 256 + col];
      const float u = (fv - hv) / gvv;
      atomicAdd(&ebuck[row / 50], 0.001f * u * u);
      const float znew = ztile[rl][col_loc] + 0.1f * fv +
                         gvv * (SQRTH * dw[(size_t)t * (EB_ * 256) + (size_t)row * 256 + col]);
      const bf16 h = __float2bfloat16(znew);
      const size_t zi = (size_t)row * 256 + col;
      zhi[zi] = h;
      zlo[zi] = __float2bfloat16(znew - __bfloat162float(h));
      const int e = row / 50, b = row - e * 50;
      zs_bf[((size_t)e * TB_ + t * 50 + b) * 256 + col] = h;
    }
  }
  __syncthreads();
  if (tid < 7) {
    const float v = ebuck[tid];
    if (v != 0.f) atomicAdd(&logqp[tid], v);
  }
}

__global__ void init_kernel(float* logqp) {
  if (threadIdx.x < E_) logqp[threadIdx.x] = 0.f;
}

extern "C" void kernel_launch(void* const* d_in, const int* in_sizes, int n_in,
                              void* d_out, int out_size, void* d_ws, size_t ws_size,
                              hipStream_t stream) {
  (void)in_sizes; (void)n_in; (void)out_size;
  const float* enc_w1 = (const float*)d_in[0];
  const float* enc_b1 = (const float*)d_in[1];
  const float* enc_w2 = (const float*)d_in[2];
  const float* enc_b2 = (const float*)d_in[3];
  const float* enc_w3 = (const float*)d_in[4];
  const float* enc_b3 = (const float*)d_in[5];
  const float* qz0_w  = (const float*)d_in[6];
  const float* qz0_b  = (const float*)d_in[7];
  const float* act_w  = (const float*)d_in[8];
  const float* act_b  = (const float*)d_in[9];
  const float* proj_w1 = (const float*)d_in[10];
  const float* proj_b1 = (const float*)d_in[11];
  const float* proj_w2 = (const float*)d_in[12];
  const float* proj_b2 = (const float*)d_in[13];
  const float* proj_w3 = (const float*)d_in[14];
  const float* proj_b3 = (const float*)d_in[15];
  const float* f_w1 = (const float*)d_in[16];
  const float* f_b1 = (const float*)d_in[17];
  const float* f_w2 = (const float*)d_in[18];
  const float* f_b2 = (const float*)d_in[19];
  const float* f_w3 = (const float*)d_in[20];
  const float* f_b3 = (const float*)d_in[21];
  const float* h_w1 = (const float*)d_in[22];
  const float* h_b1 = (const float*)d_in[23];
  const float* h_w2 = (const float*)d_in[24];
  const float* h_b2 = (const float*)d_in[25];
  const float* h_w3 = (const float*)d_in[26];
  const float* h_b3 = (const float*)d_in[27];
  const float* g_w1 = (const float*)d_in[28];
  const float* g_b1 = (const float*)d_in[29];
  const float* g_w2 = (const float*)d_in[30];
  const float* g_b2 = (const float*)d_in[31];
  const float* pz0_mean   = (const float*)d_in[32];
  const float* pz0_logstd = (const float*)d_in[33];
  const float* xs      = (const float*)d_in[34];
  const float* actions = (const float*)d_in[35];
  const float* eps_z0  = (const float*)d_in[36];
  const float* dw      = (const float*)d_in[37];

  float* out = (float*)d_out;
  float* logqp = out;
  float* pred = out + E_;

  char* base = (char*)d_ws;
  size_t off = 0;
  auto alloc = [&](size_t bytes) {
    void* p = base + off;
    off = (off + bytes + 255) & ~(size_t)255;
    return p;
  };
  bf16* zhi    = (bf16*)alloc((size_t)EB_ * 256 * 2);
  bf16* zlo    = (bf16*)alloc((size_t)EB_ * 256 * 2);
  float* zP    = (float*)alloc((size_t)EB_ * 256 * 4);
  bf16* zPb    = (bf16*)alloc((size_t)EB_ * 256 * 2);
  bf16* fh1    = (bf16*)alloc((size_t)EB_ * 2048 * 2);
  bf16* fh2    = (bf16*)alloc((size_t)EB_ * 2048 * 2);
  float* gvb   = (float*)alloc((size_t)EB_ * 256 * 4);
  bf16* zs_bf  = (bf16*)alloc((size_t)E_ * T_ * B_ * 256 * 2);
  float* axw   = (float*)alloc((size_t)E_ * TB_ * 256 * 4);
  bf16* ax_bf  = (bf16*)alloc((size_t)E_ * TB_ * 192 * 2);
  bf16* waxT   = (bf16*)alloc((size_t)E_ * 256 * 192 * 2);
  bf16* wzh    = (bf16*)alloc((size_t)E_ * 65536 * 2);
  bf16* wzl    = (bf16*)alloc((size_t)E_ * 65536 * 2);
  bf16* w1f    = (bf16*)alloc((size_t)2048 * 256 * 2);
  bf16* w2f    = (bf16*)alloc((size_t)2048 * 1024 * 2);
  bf16* w3f    = (bf16*)alloc((size_t)512 * 1024 * 2);
  _Float16* gpk = (_Float16*)alloc((size_t)256 * 3 * 1024 * 2);
  bf16* xs_bf  = (bf16*)alloc((size_t)E_ * TB_ * D_ * 2);
  bf16* ew1T = (bf16*)alloc((size_t)E_ * D_ * H_ * 2);
  bf16* ew2T = (bf16*)alloc((size_t)E_ * H_ * H_ * 2);
  bf16* ew3T = (bf16*)alloc((size_t)E_ * H_ * C_ * 2);
  bf16* pw1T = (bf16*)alloc((size_t)E_ * L_ * H_ * 2);
  bf16* pw2T = (bf16*)alloc((size_t)E_ * H_ * H_ * 2);
  bf16* pw3T = (bf16*)alloc((size_t)E_ * H_ * D_ * 2);
  const size_t per_row = (size_t)E_ * (H_ * 2 * 2 + C_ * 4);
  size_t remain = (ws_size > off + 4096) ? (ws_size - off - 4096) : 0;
  int CH = (int)(remain / per_row);
  if (CH > 2500) CH = 2500;
  if (CH < 64) CH = 64;
  bf16* bufA = (bf16*)alloc((size_t)E_ * CH * H_ * 2);
  bf16* bufB = (bf16*)alloc((size_t)E_ * CH * H_ * 2);
  float* bufC = (float*)alloc((size_t)E_ * CH * C_ * 4);

  init_kernel<<<dim3(1), dim3(64), 0, stream>>>(logqp);

  const dim3 cb256(256);
  cvt_kernel<<<dim3((E_ * TB_ * D_ / 4 + 255) / 256), cb256, 0, stream>>>(xs, xs_bf, E_ * TB_ * D_ / 4);
  cvtT_kernel<<<dim3(H_ / 32, D_ / 32, E_), cb256, 0, stream>>>(enc_w1, ew1T, D_, H_, (long)D_ * H_, (long)D_ * H_);
  cvtT_kernel<<<dim3(H_ / 32, H_ / 32, E_), cb256, 0, stream>>>(enc_w2, ew2T, H_, H_, (long)H_ * H_, (long)H_ * H_);
  cvtT_kernel<<<dim3(C_ / 32, H_ / 32, E_), cb256, 0, stream>>>(enc_w3, ew3T, H_, C_, (long)H_ * C_, (long)H_ * C_);
  cvtT_kernel<<<dim3(H_ / 32, L_ / 32, E_), cb256, 0, stream>>>(proj_w1, pw1T, L_, H_, (long)L_ * H_, (long)L_ * H_);
  cvtT_kernel<<<dim3(H_ / 32, H_ / 32, E_), cb256, 0, stream>>>(proj_w2, pw2T, H_, H_, (long)H_ * H_, (long)H_ * H_);
  cvtT_kernel<<<dim3(D_ / 32, H_ / 32, E_), cb256, 0, stream>>>(proj_w3, pw3T, H_, D_, (long)H_ * D_, (long)H_ * D_);
  ax_build<<<dim3((E_ * TB_ * 192 + 255) / 256), cb256, 0, stream>>>(actions, xs, ax_bf);
  waxT_build<<<dim3((E_ * 256 * 192 + 255) / 256), cb256, 0, stream>>>(act_w, waxT);
  packWz<<<dim3((E_ * 65536 + 255) / 256), cb256, 0, stream>>>(act_w, wzh, wzl);
  packW<<<dim3((256 * 1024 + 255) / 256), cb256, 0, stream>>>(f_w1, w1f, 256, 1024);
  packW<<<dim3((256 * 1024 + 255) / 256), cb256, 0, stream>>>(h_w1, w1f + (size_t)1024 * 256, 256, 1024);
  packW<<<dim3((1024 * 1024 + 255) / 256), cb256, 0, stream>>>(f_w2, w2f, 1024, 1024);
  packW<<<dim3((1024 * 1024 + 255) / 256), cb256, 0, stream>>>(h_w2, w2f + (size_t)1024 * 1024, 1024, 1024);
  packW<<<dim3((1024 * 256 + 255) / 256), cb256, 0, stream>>>(f_w3, w3f, 1024, 256);
  packW<<<dim3((1024 * 256 + 255) / 256), cb256, 0, stream>>>(h_w3, w3f + (size_t)256 * 1024, 1024, 256);
  gpack_build<<<dim3((256 * 3 * 1024 + 255) / 256), cb256, 0, stream>>>(g_w1, g_b1, g_w2, gpk);

  BG g;
  // axw = ax @ WaxT + act_b  (all t, f32)
  for (int e = 0; e < E_; ++e) {
    g.A[e] = ax_bf + (size_t)e * TB_ * 192;
    g.W[e] = waxT + (size_t)e * 256 * 192;
    g.bias[e] = act_b + (size_t)e * 256;
    g.Cf[e] = axw + (size_t)e * TB_ * 256;
  }
  bgemm<128, 0, 0><<<dim3((TB_ + 127) / 128, 2, E_), 256, 0, stream>>>(g, TB_, 192, 192, 192, 256);

  // ---- Phase A: encoder + q/KL (+z0 split into zhi/zlo) ----
  for (int c = 0; c < TB_; c += CH) {
    const int rows = (TB_ - c < CH) ? (TB_ - c) : CH;
    const int mt = (rows + 127) / 128;
    for (int e = 0; e < E_; ++e) {
      g.A[e] = xs_bf + ((size_t)e * TB_ + c) * D_;
      g.W[e] = ew1T + (size_t)e * D_ * H_;
      g.bias[e] = enc_b1 + (size_t)e * H_;
      g.Cb[e] = bufA + (size_t)e * CH * H_;
    }
    bgemm<128, 1, 1><<<dim3(mt, H_ / 128, E_), 256, 0, stream>>>(g, rows, D_, D_, D_, H_);
    for (int e = 0; e < E_; ++e) {
      g.A[e] = bufA + (size_t)e * CH * H_;
      g.W[e] = ew2T + (size_t)e * H_ * H_;
      g.bias[e] = enc_b2 + (size_t)e * H_;
      g.Cb[e] = bufB + (size_t)e * CH * H_;
    }
    bgemm<128, 1, 1><<<dim3(mt, H_ / 128, E_), 256, 0, stream>>>(g, rows, H_, H_, H_, H_);
    for (int e = 0; e < E_; ++e) {
      g.A[e] = bufB + (size_t)e * CH * H_;
      g.W[e] = ew3T + (size_t)e * H_ * C_;
      g.bias[e] = enc_b3 + (size_t)e * C_;
      g.Cf[e] = bufC + (size_t)e * CH * C_;
    }
    bgemm<128, 0, 0><<<dim3(mt, C_ / 128, E_), 256, 0, stream>>>(g, rows, H_, H_, H_, C_);
    qkl_kernel<<<dim3((rows + 15) / 16, E_), 256, 0, stream>>>(
        bufC, rows, c, CH * C_, qz0_w, qz0_b, pz0_mean, pz0_logstd, eps_z0,
        zhi, zlo, logqp);
  }

  // ---- Scan: 4 kernels per step (g overlapped with L2 in k3g) ----
  for (int t = 0; t < T_; ++t) {
    k1_act<<<dim3(4, 2, E_), 256, 0, stream>>>(zhi, zlo, wzh, wzl, axw, zP, zPb, t);
    k2_l1<<<dim3(22, 16), 256, 0, stream>>>(zPb, w1f, f_b1, h_b1, fh1);
    k3g<<<dim3(22, 20), 256, 0, stream>>>(fh1, w2f, f_b2, h_b2, fh2,
                                          zP, gpk, g_b2, gvb);
    k4_fin<<<dim3(22, 4), 256, 0, stream>>>(fh2, w3f, f_b3, h_b3, gvb,
                                            zP, dw, zhi, zlo, zs_bf, logqp, t);
  }

  // ---- Projector ----
  for (int c = 0; c < TB_; c += CH) {
    const int rows = (TB_ - c < CH) ? (TB_ - c) : CH;
    const int mt = (rows + 127) / 128;
    for (int e = 0; e < E_; ++e) {
      g.A[e] = zs_bf + ((size_t)e * T_ * B_ + c) * L_;
      g.W[e] = pw1T + (size_t)e * L_ * H_;
      g.bias[e] = proj_b1 + (size_t)e * H_;
      g.Cb[e] = bufA + (size_t)e * CH * H_;
    }
    bgemm<128, 2, 1><<<dim3(mt, H_ / 128, E_), 256, 0, stream>>>(g, rows, L_, L_, L_, H_);
    for (int e = 0; e < E_; ++e) {
      g.A[e] = bufA + (size_t)e * CH * H_;
      g.W[e] = pw2T + (size_t)e * H_ * H_;
      g.bias[e] = proj_b2 + (size_t)e * H_;
      g.Cb[e] = bufB + (size_t)e * CH * H_;
    }
    bgemm<128, 2, 1><<<dim3(mt, H_ / 128, E_), 256, 0, stream>>>(g, rows, H_, H_, H_, H_);
    for (int e = 0; e < E_; ++e) {
      g.A[e] = bufB + (size_t)e * CH * H_;
      g.W[e] = pw3T + (size_t)e * H_ * D_;
      g.bias[e] = proj_b3 + (size_t)e * D_;
      g.Cf[e] = pred + ((size_t)e * TB_ + c) * D_;
    }
    bgemm<128, 0, 0><<<dim3(mt, D_ / 128, E_), 256, 0, stream>>>(g, rows, H_, H_, H_, D_);
  }
}